// Round 2
// baseline (90273.376 us; speedup 1.0000x reference)
//
#include <hip/hip_runtime.h>
#include <cmath>

typedef _Float16 f16;
typedef _Float16 f16x8 __attribute__((ext_vector_type(8)));
typedef float f32x4 __attribute__((ext_vector_type(4)));

#define MFMA_F16(a,b,c) __builtin_amdgcn_mfma_f32_16x16x32_f16((a),(b),(c),0,0,0)

// N=64, A=128, MO=126, LX=96, H=1024, S=32, P=2, B=16, BL=32, T=448
// IN=382 (pad 384), GIN=1406
#define TSTEPS 448
#define OFF_MU 3612672   // 64*126*448
#define OFF_LV 4530176   // + 64*32*448
#define LDS_BYTES 143360 // 140 KB dynamic LDS per block (weights stay resident)

struct Ptrs {
  const float *aud, *mo, *lxm, *eps;
  const int *vid;
  const float *csi_w0, *csi_b0, *csi_w1, *csi_b1, *csi_w2, *csi_b2;
  const float *spk, *mu_w, *mu_b, *lv_w, *lv_b;
  const float *embW, *embB;
  const float *wih0, *whh0, *bih0, *bhh0;
  const float *wih1, *whh1, *bih1, *bhh1;
  const float *ln_g, *ln_b, *predW, *predB;
  float *out;
  unsigned *bar;
  float *part, *mu5, *lv5, *h0F, *h1F;
  f16 *h0B, *h1B, *ineB, *xcat;
  float *gh0, *gh1, *gi0p, *x0, *x1, *predsT;
  f16 *whh0P, *whh1P, *wih0aP, *wih0bP, *wih1P, *embWP, *predWP;
};

__device__ __forceinline__ float geluf(float x) {
  return 0.5f * x * (1.0f + erff(x * 0.7071067811865475f));
}
__device__ __forceinline__ float sigmf(float x) {
  return 1.0f / (1.0f + expf(-x));
}

// ---------------- prologue kernels ----------------

__global__ void k_init(Ptrs p) {
  if (threadIdx.x < 256) p.bar[threadIdx.x] = 0u;
}

// Pack W rows [rowOff, rowOff+K) of a (?,ldN) fp32 row-major matrix into MFMA
// B-fragment tiles: dst[(ct*nkt + kt)*512 + l*8 + i] = W[kt*32+(l>>4)*8+i][ct*16+(l&15)]
__global__ void k_pack(const float* __restrict__ src, f16* __restrict__ dst,
                       int K, int rowOff, int realN, int ldN) {
  int ct = blockIdx.x, kt = blockIdx.y;
  int e = threadIdx.x * 2;
  int l = e >> 3, i = e & 7;
  int k = kt * 32 + (l >> 4) * 8 + i;
  int col = ct * 16 + (l & 15);
  f16 v0 = (f16)0.f, v1 = (f16)0.f;
  if (k < K && col < realN)     v0 = (f16)src[(size_t)(rowOff + k) * ldN + col];
  if (k + 1 < K && col < realN) v1 = (f16)src[(size_t)(rowOff + k + 1) * ldN + col];
  size_t o = ((size_t)ct * gridDim.y + kt) * 512 + e;
  dst[o] = v0; dst[o + 1] = v1;
}

__global__ void k_csi1(Ptrs p) {
  int gid = blockIdx.x * 256 + threadIdx.x;  // 65536
  int n = gid >> 10, c = gid & 1023;
  float acc = p.csi_b0[c];
  const float* w = p.csi_w0 + c;
  for (int k = 0; k < 126; k++) acc += p.mo[((size_t)(n * 126 + k)) * 512 + 31] * w[(size_t)k * 1024];
  for (int k = 0; k < 96; k++)  acc += p.lxm[(size_t)(n * 96 + k) * 16] * w[(size_t)(126 + k) * 1024];
  p.x0[gid] = geluf(acc);
}

__global__ void k_csi2(Ptrs p) {
  int gid = blockIdx.x * 256 + threadIdx.x;
  int n = gid >> 10, c = gid & 1023;
  float acc = p.csi_b1[c];
  const float* w = p.csi_w1 + c;
  const float* x = p.x0 + (size_t)n * 1024;
  for (int k = 0; k < 1024; k++) acc += x[k] * w[(size_t)k * 1024];
  p.x1[gid] = geluf(acc);
}

__global__ void k_csi3(Ptrs p) {
  int gid = blockIdx.x * 256 + threadIdx.x;  // 131072
  int n = gid >> 11, c2 = gid & 2047;
  float acc = p.csi_b2[c2];
  const float* w = p.csi_w2 + c2;
  const float* x = p.x1 + (size_t)n * 1024;
  for (int k = 0; k < 1024; k++) acc += x[k] * w[(size_t)k * 2048];
  if (c2 < 1024) { p.h0F[n * 1024 + c2] = acc; p.h0B[n * 1024 + c2] = (f16)acc; }
  else           { p.h1F[n * 1024 + c2 - 1024] = acc; p.h1B[n * 1024 + c2 - 1024] = (f16)acc; }
}

__global__ void k_gh(Ptrs p) {  // initial gh0/gh1 for t=0 (scalar, one-time)
  int gid = blockIdx.x * 256 + threadIdx.x;  // 393216
  int which = gid >= 196608;
  int g2 = which ? gid - 196608 : gid;
  int n = g2 / 3072, c = g2 % 3072;
  const float* h = which ? p.h1F : p.h0F;
  const float* W = which ? p.whh1 : p.whh0;
  const float* bb = which ? p.bhh1 : p.bhh0;
  float acc = bb[c];
  const float* hr = h + (size_t)n * 1024;
  for (int k = 0; k < 1024; k++) acc += hr[k] * W[(size_t)k * 3072 + c];
  (which ? p.gh1 : p.gh0)[(size_t)n * 3072 + c] = acc;
}

__global__ void k_style1(Ptrs p) {
  int tid = threadIdx.x;
  if (tid < 160) {
    int v = tid >> 5, s = tid & 31;
    float m = p.mu_b[s], lv = p.lv_b[s];
    for (int k = 0; k < 32; k++) {
      float z = p.spk[v * 32 + k];
      m += z * p.mu_w[k * 32 + s];
      lv += z * p.lv_w[k * 32 + s];
    }
    p.mu5[v * 32 + s] = m; p.lv5[v * 32 + s] = lv;
  }
}

__global__ void k_style2(Ptrs p) {
  int gid = blockIdx.x * 256 + threadIdx.x;  // 917504
  int t = gid % 448;
  int rr = gid / 448;
  int s = rr & 31, n = rr >> 5;
  int v = p.vid[n * 16 + (t >> 5) + 1];
  float mu = p.mu5[v * 32 + s], lv = p.lv5[v * 32 + s];
  float e = p.eps[((size_t)t * 64 + n) * 32 + s];
  float st = mu + e * expf(0.5f * lv);
  p.out[OFF_MU + ((size_t)n * 32 + s) * 448 + t] = mu;
  p.out[OFF_LV + ((size_t)n * 32 + s) * 448 + t] = lv;
  p.xcat[((size_t)t * 64 + n) * 384 + 350 + s] = (f16)st;
}

__global__ void k_aud(Ptrs p) {
  __shared__ float tile[32][65];
  int bid = blockIdx.x;  // 64*4*7
  int n = bid / 28, rem = bid % 28;
  int a0 = (rem / 7) * 32, t0 = (rem % 7) * 64;
  int tid = threadIdx.x;
  for (int i = tid; i < 2048; i += 256) {
    int ai = i >> 6, tj = i & 63;
    tile[ai][tj] = p.aud[((size_t)n * 128 + a0 + ai) * 448 + t0 + tj];
  }
  __syncthreads();
  for (int i = tid; i < 2048; i += 256) {
    int tj = i >> 5, ai = i & 31;
    p.xcat[((size_t)(t0 + tj) * 64 + n) * 384 + 126 + a0 + ai] = (f16)tile[ai][tj];
  }
}

__global__ void k_lxm(Ptrs p) {
  int gid = blockIdx.x * 256 + threadIdx.x;  // 2752512
  int l_ = gid % 96;
  int r = gid / 96;
  int n = r & 63, t = r >> 6;
  int tb = (t >> 5) + 1;
  p.xcat[((size_t)t * 64 + n) * 384 + 254 + l_] = (f16)p.lxm[((size_t)n * 96 + l_) * 16 + tb];
}

__global__ void k_premo0(Ptrs p) {
  int gid = blockIdx.x * 256 + threadIdx.x;
  if (gid < 8064) {
    int n = gid / 126, m = gid % 126;
    p.xcat[(size_t)n * 384 + m] = (f16)p.mo[((size_t)n * 126 + m) * 512 + 31];
  }
}

__global__ void k_padz(Ptrs p) {  // zero xcat pad cols 382,383 for all (t,n)
  int gid = blockIdx.x * 256 + threadIdx.x;  // 57344
  int t = gid >> 7, rem = gid & 127;
  int n = rem >> 1, c = 382 + (rem & 1);
  p.xcat[((size_t)t * 64 + n) * 384 + c] = (f16)0.f;
}

// ---------------- persistent scan kernel ----------------

__device__ __forceinline__ void gbar(unsigned* bar, unsigned& epoch, int b) {
  __syncthreads();
  __threadfence();  // release: make this phase's stores visible (cross-XCD)
  int tid = threadIdx.x;
  if (tid == 0)
    __hip_atomic_fetch_add(&bar[(b & 7) << 5], 1u, __ATOMIC_RELAXED, __HIP_MEMORY_SCOPE_AGENT);
  epoch++;
  if (tid < 8) {
    unsigned tgt = epoch * 32u;
    while (__hip_atomic_load(&bar[tid << 5], __ATOMIC_RELAXED, __HIP_MEMORY_SCOPE_AGENT) < tgt)
      __builtin_amdgcn_s_sleep(2);
  }
  __syncthreads();
  __threadfence();  // acquire
}

__global__ __launch_bounds__(256, 1) void k_scan(Ptrs p) {
  extern __shared__ char smem[];
  f16* L = (f16*)smem;
  const int b = blockIdx.x, tid = threadIdx.x;
  const int w = tid >> 6, l = tid & 63;
  const int lm = l & 15, lq = l >> 4;
  unsigned epoch = 0;

  // ---- one-time: stage this block's weight tiles into LDS (resident forever) ----
  {
    auto cp = [&](int dstF16, const f16* src, int nF16) {
      uint4* d = (uint4*)smem + (dstF16 >> 3);
      const uint4* s = (const uint4*)src;
      for (int i = tid; i < (nF16 >> 3); i += 256) d[i] = s[i];
    };
    if (b < 64) {  // B-block: wih0a 3 gates (96K) + gi0p tile (12K) + gh0 tile (32K)
      cp(0,     p.wih0aP + (size_t)b * 16384, 16384);
      cp(16384, p.wih0aP + (size_t)(64 + b) * 16384, 16384);
      cp(32768, p.wih0aP + (size_t)(128 + b) * 16384, 16384);
      cp(49152, p.wih0bP + (size_t)b * 6144, 6144);
      cp(55296, p.whh0P + (size_t)b * 16384, 16384);
    } else if (b < 128) {  // C-block: wih1 3 gates + gi0p tile + gh0 tile
      int cb = b - 64;
      cp(0,     p.wih1P + (size_t)cb * 16384, 16384);
      cp(16384, p.wih1P + (size_t)(64 + cb) * 16384, 16384);
      cp(32768, p.wih1P + (size_t)(128 + cb) * 16384, 16384);
      cp(49152, p.wih0bP + (size_t)b * 6144, 6144);
      cp(55296, p.whh0P + (size_t)b * 16384, 16384);
    } else {  // A-block: P1 tile (12K) + 2 gh units (64K) + pred (32K, first 8)
      int i = b - 128;
      if (b < 192) cp(0, p.wih0bP + (size_t)b * 6144, 6144);
      else         cp(0, p.embWP + (size_t)(b - 192) * 6144, 6144);
      cp(6144, (i < 64) ? (p.whh0P + (size_t)(128 + i) * 16384)
                        : (p.whh1P + (size_t)(i - 64) * 16384), 16384);
      cp(22528, p.whh1P + (size_t)(64 + i) * 16384, 16384);
      if (i < 8) cp(38912, p.predWP + (size_t)i * 16384, 16384);
    }
  }
  __syncthreads();

  for (int t = 0; t < TSTEPS; t++) {
    const f16* xc = p.xcat + (size_t)t * 24576;

    // ======== P1: gi0p tile (blocks 0..191) / ine tile (blocks 192..255) ========
    {
      const f16* wlds = L + ((b < 128) ? 49152 : 0);
      f32x4 acc = {0.f, 0.f, 0.f, 0.f};
      const f16* aB = xc + (w * 16 + lm) * 384 + lq * 8;
      const f16* bB = wlds + l * 8;
      #pragma unroll
      for (int kt = 0; kt < 12; kt++)
        acc = MFMA_F16(*(const f16x8*)(aB + kt * 32), *(const f16x8*)(bB + kt * 512), acc);
      int row0 = w * 16 + lq * 4;
      if (b < 192) {
        int col = b * 16 + lm;
        float bv = p.bih0[col];
        #pragma unroll
        for (int r = 0; r < 4; r++) p.gi0p[(size_t)(row0 + r) * 3072 + col] = acc[r] + bv;
      } else {
        int col = (b - 192) * 16 + lm;
        float bv = p.embB[col];
        #pragma unroll
        for (int r = 0; r < 4; r++) p.ineB[(size_t)(row0 + r) * 1024 + col] = (f16)geluf(acc[r] + bv);
      }
    }
    gbar(p.bar, epoch, b);

    // ======== B: gi0a GEMM + fused GRU-0 elementwise -> h0n (blocks 0..63) ========
    if (b < 64) {
      f32x4 ar = {0,0,0,0}, az = {0,0,0,0}, an = {0,0,0,0};
      const f16* aB = p.ineB + (w * 16 + lm) * 1024 + lq * 8;
      const f16* b0 = L + l * 8;
      #pragma unroll 4
      for (int kt = 0; kt < 32; kt++) {
        f16x8 av = *(const f16x8*)(aB + kt * 32);
        ar = MFMA_F16(av, *(const f16x8*)(b0 + kt * 512), ar);
        az = MFMA_F16(av, *(const f16x8*)(b0 + 16384 + kt * 512), az);
        an = MFMA_F16(av, *(const f16x8*)(b0 + 32768 + kt * 512), an);
      }
      int col = b * 16 + lm;
      int row0 = w * 16 + lq * 4;
      #pragma unroll
      for (int r = 0; r < 4; r++) {
        int row = row0 + r;
        const float* gp = p.gi0p + (size_t)row * 3072;
        const float* gh = p.gh0 + (size_t)row * 3072;
        float r_ = sigmf(ar[r] + gp[col] + gh[col]);
        float z_ = sigmf(az[r] + gp[1024 + col] + gh[1024 + col]);
        float n_ = tanhf(an[r] + gp[2048 + col] + r_ * 0.f + gh[2048 + col] * 0.f + r_ * gh[2048 + col]);
        float* hf = p.h0F + (size_t)row * 1024 + col;
        float hn = (1.f - z_) * n_ + z_ * (*hf);
        *hf = hn;
        p.h0B[(size_t)row * 1024 + col] = (f16)hn;
      }
    }
    gbar(p.bar, epoch, b);

    // ======== C: gi1 GEMM + fused GRU-1 elementwise -> h1n + LN partials (blocks 64..127) ========
    if (b >= 64 && b < 128) {
      f32x4 ar = {0,0,0,0}, az = {0,0,0,0}, an = {0,0,0,0};
      const f16* aB = p.h0B + (w * 16 + lm) * 1024 + lq * 8;
      const f16* b0 = L + l * 8;
      #pragma unroll 4
      for (int kt = 0; kt < 32; kt++) {
        f16x8 av = *(const f16x8*)(aB + kt * 32);
        ar = MFMA_F16(av, *(const f16x8*)(b0 + kt * 512), ar);
        az = MFMA_F16(av, *(const f16x8*)(b0 + 16384 + kt * 512), az);
        an = MFMA_F16(av, *(const f16x8*)(b0 + 32768 + kt * 512), an);
      }
      int cb = b - 64;
      int col = cb * 16 + lm;
      int row0 = w * 16 + lq * 4;
      float sv[4], sq[4];
      #pragma unroll
      for (int r = 0; r < 4; r++) {
        int row = row0 + r;
        const float* gh = p.gh1 + (size_t)row * 3072;
        float r_ = sigmf(ar[r] + p.bih1[col] + gh[col]);
        float z_ = sigmf(az[r] + p.bih1[1024 + col] + gh[1024 + col]);
        float n_ = tanhf(an[r] + p.bih1[2048 + col] + r_ * gh[2048 + col]);
        float* hf = p.h1F + (size_t)row * 1024 + col;
        float hn = (1.f - z_) * n_ + z_ * (*hf);
        *hf = hn;
        p.h1B[(size_t)row * 1024 + col] = (f16)hn;
        sv[r] = hn; sq[r] = hn * hn;
      }
      #pragma unroll
      for (int m = 1; m < 16; m <<= 1) {
        #pragma unroll
        for (int r = 0; r < 4; r++) { sv[r] += __shfl_xor(sv[r], m); sq[r] += __shfl_xor(sq[r], m); }
      }
      if (lm == 0) {
        #pragma unroll
        for (int r = 0; r < 4; r++) {
          int row = row0 + r;
          p.part[cb * 128 + row * 2] = sv[r];
          p.part[cb * 128 + row * 2 + 1] = sq[r];
        }
      }
    }
    gbar(p.bar, epoch, b);

    // ======== P4: pred (blocks 128..135) + next-step gh0/gh1 (all blocks) ========
    if (b >= 128 && b < 136) {
      float* statsS = (float*)(smem + 110592);
      if (tid < 128) {
        float s = 0.f;
        #pragma unroll 8
        for (int cb = 0; cb < 64; cb++) s += p.part[cb * 128 + tid];
        statsS[tid] = s;
      }
      __syncthreads();
      int ct = b - 128;
      int myrow = w * 16 + lm;
      float mean = statsS[myrow * 2] * 0.0009765625f;
      float var  = statsS[myrow * 2 + 1] * 0.0009765625f - mean * mean;
      float rstd = rsqrtf(var + 1e-5f);
      f32x4 acc = {0,0,0,0};
      const f16* hB = p.h1B + (size_t)myrow * 1024;
      const f16* bB = L + 38912 + l * 8;
      #pragma unroll 4
      for (int kt = 0; kt < 32; kt++) {
        int k0 = kt * 32 + lq * 8;
        f16x8 hv = *(const f16x8*)(hB + k0);
        f16x8 af;
        #pragma unroll
        for (int e = 0; e < 8; e++)
          af[e] = (f16)((((float)hv[e]) - mean) * rstd * p.ln_g[k0 + e] + p.ln_b[k0 + e]);
        acc = MFMA_F16(af, *(const f16x8*)(bB + kt * 512), acc);
      }
      int col = ct * 16 + lm;
      if (col < 126) {
        #pragma unroll
        for (int r = 0; r < 4; r++) {
          int row = w * 16 + lq * 4 + r;
          float v = acc[r] + p.predB[col];
          p.predsT[(size_t)t * 8064 + row * 126 + col] = v;
          if (t < 447) p.xcat[(size_t)(t + 1) * 24576 + row * 384 + col] = (f16)v;
        }
      }
    }
    {
      auto ghUnit = [&](const f16* wlds, const f16* act, float* outB, const float* bias, int ct) {
        f32x4 acc = {0,0,0,0};
        const f16* aB = act + (w * 16 + lm) * 1024 + lq * 8;
        #pragma unroll 4
        for (int kt = 0; kt < 32; kt++)
          acc = MFMA_F16(*(const f16x8*)(aB + kt * 32), *(const f16x8*)(wlds + kt * 512 + l * 8), acc);
        int col = ct * 16 + lm;
        float bv = bias[col];
        #pragma unroll
        for (int r = 0; r < 4; r++)
          outB[(size_t)(w * 16 + lq * 4 + r) * 3072 + col] = acc[r] + bv;
      };
      if (b < 128) {
        ghUnit(L + 55296, p.h0B, p.gh0, p.bhh0, b);
      } else {
        int i = b - 128;
        if (i < 64) ghUnit(L + 6144, p.h0B, p.gh0, p.bhh0, 128 + i);
        else        ghUnit(L + 6144, p.h1B, p.gh1, p.bhh1, i - 64);
        ghUnit(L + 22528, p.h1B, p.gh1, p.bhh1, 64 + i);
      }
    }
    gbar(p.bar, epoch, b);
  }

  // ======== epilogue: predsT (t,n,m) -> out (n,m,t) ========
  {
    float* trS = (float*)smem;  // weights dead now; reuse LDS
    for (int g = b; g < 504; g += 256) {
      int p0 = g * 16;
      for (int t0 = 0; t0 < 448; t0 += 16) {
        int tc = tid >> 4, pp = tid & 15;
        trS[tc * 17 + pp] = p.predsT[(size_t)(t0 + tc) * 8064 + p0 + pp];
        __syncthreads();
        p.out[(size_t)(p0 + (tid >> 4)) * 448 + t0 + (tid & 15)] = trS[(tid & 15) * 17 + (tid >> 4)];
        __syncthreads();
      }
    }
  }
}

// ---------------- host ----------------

extern "C" void kernel_launch(void* const* d_in, const int* in_sizes, int n_in,
                              void* d_out, int out_size, void* d_ws, size_t ws_size,
                              hipStream_t stream) {
  Ptrs p;
  p.aud = (const float*)d_in[0];
  p.mo  = (const float*)d_in[1];
  p.lxm = (const float*)d_in[2];
  p.vid = (const int*)d_in[3];
  p.eps = (const float*)d_in[4];
  p.csi_w0 = (const float*)d_in[5];  p.csi_b0 = (const float*)d_in[6];
  p.csi_w1 = (const float*)d_in[7];  p.csi_b1 = (const float*)d_in[8];
  p.csi_w2 = (const float*)d_in[9];  p.csi_b2 = (const float*)d_in[10];
  p.spk  = (const float*)d_in[11];
  p.mu_w = (const float*)d_in[12];   p.mu_b = (const float*)d_in[13];
  p.lv_w = (const float*)d_in[14];   p.lv_b = (const float*)d_in[15];
  p.embW = (const float*)d_in[16];   p.embB = (const float*)d_in[17];
  p.wih0 = (const float*)d_in[18];   p.whh0 = (const float*)d_in[19];
  p.bih0 = (const float*)d_in[20];   p.bhh0 = (const float*)d_in[21];
  p.wih1 = (const float*)d_in[22];   p.whh1 = (const float*)d_in[23];
  p.bih1 = (const float*)d_in[24];   p.bhh1 = (const float*)d_in[25];
  p.ln_g = (const float*)d_in[26];   p.ln_b = (const float*)d_in[27];
  p.predW = (const float*)d_in[28];  p.predB = (const float*)d_in[29];
  p.out = (float*)d_out;

  char* ws = (char*)d_ws;
  size_t off = 0;
  auto al = [&](size_t bytes) -> void* {
    void* r = (void*)(ws + off);
    off += (bytes + 255) & ~(size_t)255;
    return r;
  };
  p.bar    = (unsigned*)al(1024);
  p.part   = (float*)al(32768);     // [64 blocks][128] LN partials
  p.mu5    = (float*)al(640);
  p.lv5    = (float*)al(640);
  p.h0F    = (float*)al(262144);
  p.h1F    = (float*)al(262144);
  p.h0B    = (f16*)al(131072);
  p.h1B    = (f16*)al(131072);
  p.ineB   = (f16*)al(131072);
  p.gh0    = (float*)al(786432);
  p.gh1    = (float*)al(786432);
  p.gi0p   = (float*)al(786432);
  p.x0     = (float*)al(262144);
  p.x1     = (float*)al(262144);
  p.predsT = (float*)al(14450688);
  p.xcat   = (f16*)al(22020096);
  p.whh0P  = (f16*)al(6291456);
  p.whh1P  = (f16*)al(6291456);
  p.wih0aP = (f16*)al(6291456);
  p.wih0bP = (f16*)al(2359296);
  p.wih1P  = (f16*)al(6291456);
  p.embWP  = (f16*)al(786432);
  p.predWP = (f16*)al(262144);

  k_init<<<1, 256, 0, stream>>>(p);

  k_pack<<<dim3(192, 32), 256, 0, stream>>>(p.whh0, p.whh0P, 1024, 0, 3072, 3072);
  k_pack<<<dim3(192, 32), 256, 0, stream>>>(p.whh1, p.whh1P, 1024, 0, 3072, 3072);
  k_pack<<<dim3(192, 32), 256, 0, stream>>>(p.wih0, p.wih0aP, 1024, 0, 3072, 3072);
  k_pack<<<dim3(192, 12), 256, 0, stream>>>(p.wih0, p.wih0bP, 382, 1024, 3072, 3072);
  k_pack<<<dim3(192, 32), 256, 0, stream>>>(p.wih1, p.wih1P, 1024, 0, 3072, 3072);
  k_pack<<<dim3(64, 12), 256, 0, stream>>>(p.embW, p.embWP, 382, 0, 1024, 1024);
  k_pack<<<dim3(8, 32), 256, 0, stream>>>(p.predW, p.predWP, 1024, 0, 126, 126);

  k_csi1<<<256, 256, 0, stream>>>(p);
  k_csi2<<<256, 256, 0, stream>>>(p);
  k_csi3<<<512, 256, 0, stream>>>(p);
  k_gh<<<1536, 256, 0, stream>>>(p);
  k_style1<<<1, 256, 0, stream>>>(p);
  k_style2<<<3584, 256, 0, stream>>>(p);
  k_aud<<<1792, 256, 0, stream>>>(p);
  k_lxm<<<10752, 256, 0, stream>>>(p);
  k_premo0<<<32, 256, 0, stream>>>(p);
  k_padz<<<224, 256, 0, stream>>>(p);

  k_scan<<<256, 256, LDS_BYTES, stream>>>(p);

  (void)in_sizes; (void)n_in; (void)out_size; (void)ws_size;
}

// Round 3
// 27056.079 us; speedup vs baseline: 3.3365x; 3.3365x over previous
//
#include <hip/hip_runtime.h>
#include <cmath>

typedef _Float16 f16;
typedef _Float16 f16x8 __attribute__((ext_vector_type(8)));
typedef float f32x4 __attribute__((ext_vector_type(4)));

#define MFMA_F16(a,b,c) __builtin_amdgcn_mfma_f32_16x16x32_f16((a),(b),(c),0,0,0)
#define AGENT __HIP_MEMORY_SCOPE_AGENT

// N=64, A=128, MO=126, LX=96, H=1024, S=32, P=2, B=16, BL=32, T=448
#define TSTEPS 448
#define OFF_MU 3612672   // 64*126*448
#define OFF_LV 4530176   // + 64*32*448
#define LDS_BYTES 135168 // 132 KB

struct Ptrs {
  const float *aud, *mo, *lxm, *eps;
  const int *vid;
  const float *csi_w0, *csi_b0, *csi_w1, *csi_b1, *csi_w2, *csi_b2;
  const float *spk, *mu_w, *mu_b, *lv_w, *lv_b;
  const float *embW, *embB;
  const float *wih0, *whh0, *bih0, *bhh0;
  const float *wih1, *whh1, *bih1, *bhh1;
  const float *ln_g, *ln_b, *predW, *predB;
  float *out;
  unsigned *bar;
  float *stats, *mu5, *lv5, *h0F, *h1F;
  f16 *h0B, *h1B, *ineB, *xcat;
  float *gh0, *gh1, *x0, *x1, *predsT;
  f16 *whh0P, *whh1P, *wih0aP, *wih0bP, *wih1P, *embWP, *predWP;
};

__device__ __forceinline__ float geluf(float x) {
  return 0.5f * x * (1.0f + erff(x * 0.7071067811865475f));
}
__device__ __forceinline__ float sigmf(float x) {
  return 1.0f / (1.0f + expf(-x));
}

// ---- device-coherent (cross-XCD) access helpers: sc0 sc1, bypass L1/L2 ----
__device__ __forceinline__ f16x8 ldc16(const f16* p) {
  union { unsigned long long u[2]; f16x8 v; } r;
  r.u[0] = __hip_atomic_load((const unsigned long long*)p, __ATOMIC_RELAXED, AGENT);
  r.u[1] = __hip_atomic_load(((const unsigned long long*)p) + 1, __ATOMIC_RELAXED, AGENT);
  return r.v;
}
__device__ __forceinline__ float ldcf(const float* p) {
  return __hip_atomic_load(p, __ATOMIC_RELAXED, AGENT);
}
__device__ __forceinline__ void stcf(float* p, float v) {
  __hip_atomic_store(p, v, __ATOMIC_RELAXED, AGENT);
}
// pack (v, lane^1's v) into 2 f16 and store 4B coherently from even lanes
__device__ __forceinline__ void st_pair(f16* base, float v, int lm, bool pred) {
  float vn = __shfl_xor(v, 1);
  if (!(lm & 1) && pred) {
    union { f16 h[2]; unsigned u; } pk;
    pk.h[0] = (f16)v; pk.h[1] = (f16)vn;
    __hip_atomic_store((unsigned*)base, pk.u, __ATOMIC_RELAXED, AGENT);
  }
}

// ---------------- prologue kernels ----------------

__global__ void k_init(Ptrs p) {
  if (threadIdx.x < 256) p.bar[threadIdx.x] = 0u;
  if (threadIdx.x < 128) p.stats[threadIdx.x] = 0.f;
}

// Pack W rows [rowOff, rowOff+K) of a (?,ldN) fp32 row-major matrix into MFMA
// B-fragment tiles: dst[(ct*nkt + kt)*512 + l*8 + i] = W[kt*32+(l>>4)*8+i][ct*16+(l&15)]
__global__ void k_pack(const float* __restrict__ src, f16* __restrict__ dst,
                       int K, int rowOff, int realN, int ldN) {
  int ct = blockIdx.x, kt = blockIdx.y;
  int e = threadIdx.x * 2;
  int l = e >> 3, i = e & 7;
  int k = kt * 32 + (l >> 4) * 8 + i;
  int col = ct * 16 + (l & 15);
  f16 v0 = (f16)0.f, v1 = (f16)0.f;
  if (k < K && col < realN)     v0 = (f16)src[(size_t)(rowOff + k) * ldN + col];
  if (k + 1 < K && col < realN) v1 = (f16)src[(size_t)(rowOff + k + 1) * ldN + col];
  size_t o = ((size_t)ct * gridDim.y + kt) * 512 + e;
  dst[o] = v0; dst[o + 1] = v1;
}

__global__ void k_csi1(Ptrs p) {
  int gid = blockIdx.x * 256 + threadIdx.x;  // 65536
  int n = gid >> 10, c = gid & 1023;
  float acc = p.csi_b0[c];
  const float* w = p.csi_w0 + c;
  for (int k = 0; k < 126; k++) acc += p.mo[((size_t)(n * 126 + k)) * 512 + 31] * w[(size_t)k * 1024];
  for (int k = 0; k < 96; k++)  acc += p.lxm[(size_t)(n * 96 + k) * 16] * w[(size_t)(126 + k) * 1024];
  p.x0[gid] = geluf(acc);
}

__global__ void k_csi2(Ptrs p) {
  int gid = blockIdx.x * 256 + threadIdx.x;
  int n = gid >> 10, c = gid & 1023;
  float acc = p.csi_b1[c];
  const float* w = p.csi_w1 + c;
  const float* x = p.x0 + (size_t)n * 1024;
  for (int k = 0; k < 1024; k++) acc += x[k] * w[(size_t)k * 1024];
  p.x1[gid] = geluf(acc);
}

__global__ void k_csi3(Ptrs p) {
  int gid = blockIdx.x * 256 + threadIdx.x;  // 131072
  int n = gid >> 11, c2 = gid & 2047;
  float acc = p.csi_b2[c2];
  const float* w = p.csi_w2 + c2;
  const float* x = p.x1 + (size_t)n * 1024;
  for (int k = 0; k < 1024; k++) acc += x[k] * w[(size_t)k * 2048];
  if (c2 < 1024) { p.h0F[n * 1024 + c2] = acc; p.h0B[n * 1024 + c2] = (f16)acc; }
  else           { p.h1F[n * 1024 + c2 - 1024] = acc; p.h1B[n * 1024 + c2 - 1024] = (f16)acc; }
}

__global__ void k_gh(Ptrs p) {  // initial gh0/gh1 for t=0
  int gid = blockIdx.x * 256 + threadIdx.x;  // 393216
  int which = gid >= 196608;
  int g2 = which ? gid - 196608 : gid;
  int n = g2 / 3072, c = g2 % 3072;
  const float* h = which ? p.h1F : p.h0F;
  const float* W = which ? p.whh1 : p.whh0;
  const float* bb = which ? p.bhh1 : p.bhh0;
  float acc = bb[c];
  const float* hr = h + (size_t)n * 1024;
  for (int k = 0; k < 1024; k++) acc += hr[k] * W[(size_t)k * 3072 + c];
  (which ? p.gh1 : p.gh0)[(size_t)n * 3072 + c] = acc;
}

__global__ void k_style1(Ptrs p) {
  int tid = threadIdx.x;
  if (tid < 160) {
    int v = tid >> 5, s = tid & 31;
    float m = p.mu_b[s], lv = p.lv_b[s];
    for (int k = 0; k < 32; k++) {
      float z = p.spk[v * 32 + k];
      m += z * p.mu_w[k * 32 + s];
      lv += z * p.lv_w[k * 32 + s];
    }
    p.mu5[v * 32 + s] = m; p.lv5[v * 32 + s] = lv;
  }
}

__global__ void k_style2(Ptrs p) {
  int gid = blockIdx.x * 256 + threadIdx.x;  // 917504
  int t = gid % 448;
  int rr = gid / 448;
  int s = rr & 31, n = rr >> 5;
  int v = p.vid[n * 16 + (t >> 5) + 1];
  float mu = p.mu5[v * 32 + s], lv = p.lv5[v * 32 + s];
  float e = p.eps[((size_t)t * 64 + n) * 32 + s];
  float st = mu + e * expf(0.5f * lv);
  p.out[OFF_MU + ((size_t)n * 32 + s) * 448 + t] = mu;
  p.out[OFF_LV + ((size_t)n * 32 + s) * 448 + t] = lv;
  p.xcat[((size_t)t * 64 + n) * 384 + 350 + s] = (f16)st;
}

__global__ void k_aud(Ptrs p) {
  __shared__ float tile[32][65];
  int bid = blockIdx.x;  // 64*4*7
  int n = bid / 28, rem = bid % 28;
  int a0 = (rem / 7) * 32, t0 = (rem % 7) * 64;
  int tid = threadIdx.x;
  for (int i = tid; i < 2048; i += 256) {
    int ai = i >> 6, tj = i & 63;
    tile[ai][tj] = p.aud[((size_t)n * 128 + a0 + ai) * 448 + t0 + tj];
  }
  __syncthreads();
  for (int i = tid; i < 2048; i += 256) {
    int tj = i >> 5, ai = i & 31;
    p.xcat[((size_t)(t0 + tj) * 64 + n) * 384 + 126 + a0 + ai] = (f16)tile[ai][tj];
  }
}

__global__ void k_lxm(Ptrs p) {
  int gid = blockIdx.x * 256 + threadIdx.x;  // 2752512
  int l_ = gid % 96;
  int r = gid / 96;
  int n = r & 63, t = r >> 6;
  int tb = (t >> 5) + 1;
  p.xcat[((size_t)t * 64 + n) * 384 + 254 + l_] = (f16)p.lxm[((size_t)n * 96 + l_) * 16 + tb];
}

__global__ void k_premo0(Ptrs p) {
  int gid = blockIdx.x * 256 + threadIdx.x;
  if (gid < 8064) {
    int n = gid / 126, m = gid % 126;
    p.xcat[(size_t)n * 384 + m] = (f16)p.mo[((size_t)n * 126 + m) * 512 + 31];
  }
}

__global__ void k_padz(Ptrs p) {  // zero xcat pad cols 382,383
  int gid = blockIdx.x * 256 + threadIdx.x;  // 57344
  int t = gid >> 7, rem = gid & 127;
  int n = rem >> 1, c = 382 + (rem & 1);
  p.xcat[((size_t)t * 64 + n) * 384 + c] = (f16)0.f;
}

// ---------------- persistent scan kernel ----------------

// Grid barrier: NO cache-writeback fences. All cross-block data moves via
// sc0sc1 (coherent) accesses; s_waitcnt vmcnt(0) + __syncthreads drains them
// before the signal. 8 counters, 32 blocks each.
__device__ __forceinline__ void gbar(unsigned* bar, unsigned& epoch, int b) {
  asm volatile("s_waitcnt vmcnt(0)" ::: "memory");
  __syncthreads();
  if (threadIdx.x == 0)
    __hip_atomic_fetch_add(&bar[(b & 7) << 5], 1u, __ATOMIC_RELAXED, AGENT);
  epoch++;
  if (threadIdx.x < 8) {
    unsigned tgt = epoch * 32u;
    while (__hip_atomic_load(&bar[threadIdx.x << 5], __ATOMIC_RELAXED, AGENT) < tgt)
      __builtin_amdgcn_s_sleep(2);
  }
  __syncthreads();
}

__global__ __launch_bounds__(256, 1) void k_scan(Ptrs p) {
  extern __shared__ char smem[];
  f16* L = (f16*)smem;
  const int b = blockIdx.x, tid = threadIdx.x;
  const int w = tid >> 6, l = tid & 63;
  const int lm = l & 15, lq = l >> 4;
  unsigned epoch = 0;

  // ---- one-time: stage weights into LDS (resident for whole kernel) ----
  {
    auto cp = [&](int dstF16, const f16* src, int nF16) {
      uint4* d = (uint4*)smem + (dstF16 >> 3);
      const uint4* s = (const uint4*)src;
      for (int i = tid; i < (nF16 >> 3); i += 256) d[i] = s[i];
    };
    if (b < 64) {           // B-blocks: wih0a gates r/z/n tile b + wih0b tiles {b,64+b,128+b}
      cp(0,     p.wih0aP + (size_t)b * 16384, 16384);
      cp(16384, p.wih0aP + (size_t)(64 + b) * 16384, 16384);
      cp(32768, p.wih0aP + (size_t)(128 + b) * 16384, 16384);
      cp(49152, p.wih0bP + (size_t)b * 6144, 6144);
      cp(55296, p.wih0bP + (size_t)(64 + b) * 6144, 6144);
      cp(61440, p.wih0bP + (size_t)(128 + b) * 6144, 6144);
    } else if (b < 128) {   // C-blocks: wih1 gates tile cb + embW tile cb
      int cb = b - 64;
      cp(0,     p.wih1P + (size_t)cb * 16384, 16384);
      cp(16384, p.wih1P + (size_t)(64 + cb) * 16384, 16384);
      cp(32768, p.wih1P + (size_t)(128 + cb) * 16384, 16384);
      cp(49152, p.embWP + (size_t)cb * 6144, 6144);
    } else if (b < 192) {   // gh0-blocks: whh0 tiles {i,64+i,128+i} (+ predW for i<8)
      int i = b - 128;
      cp(0,     p.whh0P + (size_t)i * 16384, 16384);
      cp(16384, p.whh0P + (size_t)(64 + i) * 16384, 16384);
      cp(32768, p.whh0P + (size_t)(128 + i) * 16384, 16384);
      if (i < 8) cp(49152, p.predWP + (size_t)i * 16384, 16384);
    } else {                // gh1-blocks: whh1 tiles {i,64+i,128+i}
      int i = b - 192;
      cp(0,     p.whh1P + (size_t)i * 16384, 16384);
      cp(16384, p.whh1P + (size_t)(64 + i) * 16384, 16384);
      cp(32768, p.whh1P + (size_t)(128 + i) * 16384, 16384);
    }
  }
  __syncthreads();

  float gip[3][4];  // B-blocks: gi0p kept in registers across P1->B

  for (int t = 0; t < TSTEPS; t++) {
    const f16* xc = p.xcat + (size_t)t * 24576;

    // ======== P1: gi0p->regs (0..63) | ine (64..127) | stats zero (128) ========
    if (b < 128) {
      const f16* aB = xc + (w * 16 + lm) * 384 + lq * 8;
      f16x8 af[12];
      #pragma unroll
      for (int kt = 0; kt < 4; kt++) af[kt] = ldc16(aB + kt * 32);   // premo region: coherent
      #pragma unroll
      for (int kt = 4; kt < 12; kt++) af[kt] = *(const f16x8*)(aB + kt * 32);  // static: cached
      if (b < 64) {
        f32x4 a0 = {0,0,0,0}, a1 = {0,0,0,0}, a2 = {0,0,0,0};
        const f16* wl = L + 49152 + l * 8;
        #pragma unroll
        for (int kt = 0; kt < 12; kt++) {
          a0 = MFMA_F16(af[kt], *(const f16x8*)(wl + kt * 512), a0);
          a1 = MFMA_F16(af[kt], *(const f16x8*)(wl + 6144 + kt * 512), a1);
          a2 = MFMA_F16(af[kt], *(const f16x8*)(wl + 12288 + kt * 512), a2);
        }
        int col = b * 16 + lm;
        #pragma unroll
        for (int r = 0; r < 4; r++) {
          gip[0][r] = a0[r] + p.bih0[col];
          gip[1][r] = a1[r] + p.bih0[1024 + col];
          gip[2][r] = a2[r] + p.bih0[2048 + col];
        }
      } else {
        int cb = b - 64;
        f32x4 acc = {0,0,0,0};
        const f16* wl = L + 49152 + l * 8;
        #pragma unroll
        for (int kt = 0; kt < 12; kt++)
          acc = MFMA_F16(af[kt], *(const f16x8*)(wl + kt * 512), acc);
        int col = cb * 16 + lm;
        float bv = p.embB[col];
        #pragma unroll
        for (int r = 0; r < 4; r++) {
          int row = w * 16 + lq * 4 + r;
          float v = geluf(acc[r] + bv);
          st_pair(p.ineB + (size_t)row * 1024 + col, v, lm, true);
        }
      }
    } else if (b == 128) {
      if (tid < 128) stcf(&p.stats[tid], 0.f);  // for next step's LN accumulation
    }
    gbar(p.bar, epoch, b);

    // ======== B: gi0a GEMM + GRU-0 -> h0n (blocks 0..63) ========
    if (b < 64) {
      float ghr[3][4];
      int col = b * 16 + lm;
      #pragma unroll
      for (int u = 0; u < 3; u++)
        #pragma unroll
        for (int r = 0; r < 4; r++)
          ghr[u][r] = ldcf(p.gh0 + (size_t)(w * 16 + lq * 4 + r) * 3072 + u * 1024 + col);
      f32x4 ar = {0,0,0,0}, az = {0,0,0,0}, an = {0,0,0,0};
      const f16* aB = p.ineB + (w * 16 + lm) * 1024 + lq * 8;
      const f16* b0 = L + l * 8;
      f16x8 pf[8];
      #pragma unroll
      for (int j = 0; j < 8; j++) pf[j] = ldc16(aB + j * 32);
      #pragma unroll
      for (int g = 0; g < 4; g++) {
        #pragma unroll
        for (int j = 0; j < 8; j++) {
          f16x8 av = pf[j];
          if (g < 3) pf[j] = ldc16(aB + ((g + 1) * 8 + j) * 32);
          int kt = g * 8 + j;
          ar = MFMA_F16(av, *(const f16x8*)(b0 + kt * 512), ar);
          az = MFMA_F16(av, *(const f16x8*)(b0 + 16384 + kt * 512), az);
          an = MFMA_F16(av, *(const f16x8*)(b0 + 32768 + kt * 512), an);
        }
      }
      #pragma unroll
      for (int r = 0; r < 4; r++) {
        int row = w * 16 + lq * 4 + r;
        float r_ = sigmf(ar[r] + gip[0][r] + ghr[0][r]);
        float z_ = sigmf(az[r] + gip[1][r] + ghr[1][r]);
        float n_ = tanhf(an[r] + gip[2][r] + r_ * ghr[2][r]);
        float* hf = p.h0F + (size_t)row * 1024 + col;
        float hn = (1.f - z_) * n_ + z_ * (*hf);
        *hf = hn;
        st_pair(p.h0B + (size_t)row * 1024 + col, hn, lm, true);
      }
    }
    gbar(p.bar, epoch, b);

    // ======== C: gi1+GRU-1 -> h1n (64..127) | gh0(t+1) (128..191) ========
    if (b >= 64 && b < 128) {
      int cb = b - 64;
      int col = cb * 16 + lm;
      float ghr[3][4];
      #pragma unroll
      for (int u = 0; u < 3; u++)
        #pragma unroll
        for (int r = 0; r < 4; r++)
          ghr[u][r] = ldcf(p.gh1 + (size_t)(w * 16 + lq * 4 + r) * 3072 + u * 1024 + col);
      f32x4 ar = {0,0,0,0}, az = {0,0,0,0}, an = {0,0,0,0};
      const f16* aB = p.h0B + (w * 16 + lm) * 1024 + lq * 8;
      const f16* b0 = L + l * 8;
      f16x8 pf[8];
      #pragma unroll
      for (int j = 0; j < 8; j++) pf[j] = ldc16(aB + j * 32);
      #pragma unroll
      for (int g = 0; g < 4; g++) {
        #pragma unroll
        for (int j = 0; j < 8; j++) {
          f16x8 av = pf[j];
          if (g < 3) pf[j] = ldc16(aB + ((g + 1) * 8 + j) * 32);
          int kt = g * 8 + j;
          ar = MFMA_F16(av, *(const f16x8*)(b0 + kt * 512), ar);
          az = MFMA_F16(av, *(const f16x8*)(b0 + 16384 + kt * 512), az);
          an = MFMA_F16(av, *(const f16x8*)(b0 + 32768 + kt * 512), an);
        }
      }
      float sv[4], sq[4];
      #pragma unroll
      for (int r = 0; r < 4; r++) {
        int row = w * 16 + lq * 4 + r;
        float r_ = sigmf(ar[r] + p.bih1[col] + ghr[0][r]);
        float z_ = sigmf(az[r] + p.bih1[1024 + col] + ghr[1][r]);
        float n_ = tanhf(an[r] + p.bih1[2048 + col] + r_ * ghr[2][r]);
        float* hf = p.h1F + (size_t)row * 1024 + col;
        float hn = (1.f - z_) * n_ + z_ * (*hf);
        *hf = hn;
        st_pair(p.h1B + (size_t)row * 1024 + col, hn, lm, true);
        sv[r] = hn; sq[r] = hn * hn;
      }
      #pragma unroll
      for (int m = 1; m < 16; m <<= 1) {
        #pragma unroll
        for (int r = 0; r < 4; r++) { sv[r] += __shfl_xor(sv[r], m); sq[r] += __shfl_xor(sq[r], m); }
      }
      if (lm == 0) {
        #pragma unroll
        for (int r = 0; r < 4; r++) {
          int row = w * 16 + lq * 4 + r;
          __hip_atomic_fetch_add(&p.stats[row * 2], sv[r], __ATOMIC_RELAXED, AGENT);
          __hip_atomic_fetch_add(&p.stats[row * 2 + 1], sq[r], __ATOMIC_RELAXED, AGENT);
        }
      }
    } else if (b >= 128 && b < 192) {
      int i = b - 128;
      f32x4 c0 = {0,0,0,0}, c1 = {0,0,0,0}, c2 = {0,0,0,0};
      const f16* aB = p.h0B + (w * 16 + lm) * 1024 + lq * 8;
      const f16* b0 = L + l * 8;
      f16x8 pf[8];
      #pragma unroll
      for (int j = 0; j < 8; j++) pf[j] = ldc16(aB + j * 32);
      #pragma unroll
      for (int g = 0; g < 4; g++) {
        #pragma unroll
        for (int j = 0; j < 8; j++) {
          f16x8 av = pf[j];
          if (g < 3) pf[j] = ldc16(aB + ((g + 1) * 8 + j) * 32);
          int kt = g * 8 + j;
          c0 = MFMA_F16(av, *(const f16x8*)(b0 + kt * 512), c0);
          c1 = MFMA_F16(av, *(const f16x8*)(b0 + 16384 + kt * 512), c1);
          c2 = MFMA_F16(av, *(const f16x8*)(b0 + 32768 + kt * 512), c2);
        }
      }
      int col = i * 16 + lm;
      #pragma unroll
      for (int r = 0; r < 4; r++) {
        int row = w * 16 + lq * 4 + r;
        stcf(&p.gh0[(size_t)row * 3072 + col],        c0[r] + p.bhh0[col]);
        stcf(&p.gh0[(size_t)row * 3072 + 1024 + col], c1[r] + p.bhh0[1024 + col]);
        stcf(&p.gh0[(size_t)row * 3072 + 2048 + col], c2[r] + p.bhh0[2048 + col]);
      }
    }
    gbar(p.bar, epoch, b);

    // ======== P4: pred (128..135) | gh1(t+1) (192..255) ========
    if (b >= 128 && b < 136) {
      int ct = b - 128;
      int myrow = w * 16 + lm;
      float s1 = ldcf(&p.stats[myrow * 2]), s2 = ldcf(&p.stats[myrow * 2 + 1]);
      float mean = s1 * 0.0009765625f;
      float var  = s2 * 0.0009765625f - mean * mean;
      float rstd = rsqrtf(var + 1e-5f);
      f32x4 acc = {0,0,0,0};
      const f16* hB = p.h1B + (size_t)myrow * 1024 + lq * 8;
      const f16* bB = L + 49152 + l * 8;
      #pragma unroll 4
      for (int kt = 0; kt < 32; kt++) {
        int k0 = kt * 32 + lq * 8;
        f16x8 hv = ldc16(hB + kt * 32);
        f16x8 af;
        #pragma unroll
        for (int e = 0; e < 8; e++)
          af[e] = (f16)((((float)hv[e]) - mean) * rstd * p.ln_g[k0 + e] + p.ln_b[k0 + e]);
        acc = MFMA_F16(af, *(const f16x8*)(bB + kt * 512), acc);
      }
      int col = ct * 16 + lm;
      float bv = (col < 126) ? p.predB[col] : 0.f;
      #pragma unroll
      for (int r = 0; r < 4; r++) {
        int row = w * 16 + lq * 4 + r;
        float v = acc[r] + bv;
        if (col < 126) stcf(&p.predsT[(size_t)t * 8064 + row * 126 + col], v);
        st_pair(p.xcat + (size_t)(t + 1) * 24576 + row * 384 + col, v, lm,
                col < 126 && t < 447);
      }
    } else if (b >= 192) {
      int i = b - 192;
      f32x4 c0 = {0,0,0,0}, c1 = {0,0,0,0}, c2 = {0,0,0,0};
      const f16* aB = p.h1B + (w * 16 + lm) * 1024 + lq * 8;
      const f16* b0 = L + l * 8;
      f16x8 pf[8];
      #pragma unroll
      for (int j = 0; j < 8; j++) pf[j] = ldc16(aB + j * 32);
      #pragma unroll
      for (int g = 0; g < 4; g++) {
        #pragma unroll
        for (int j = 0; j < 8; j++) {
          f16x8 av = pf[j];
          if (g < 3) pf[j] = ldc16(aB + ((g + 1) * 8 + j) * 32);
          int kt = g * 8 + j;
          c0 = MFMA_F16(av, *(const f16x8*)(b0 + kt * 512), c0);
          c1 = MFMA_F16(av, *(const f16x8*)(b0 + 16384 + kt * 512), c1);
          c2 = MFMA_F16(av, *(const f16x8*)(b0 + 32768 + kt * 512), c2);
        }
      }
      int col = i * 16 + lm;
      #pragma unroll
      for (int r = 0; r < 4; r++) {
        int row = w * 16 + lq * 4 + r;
        stcf(&p.gh1[(size_t)row * 3072 + col],        c0[r] + p.bhh1[col]);
        stcf(&p.gh1[(size_t)row * 3072 + 1024 + col], c1[r] + p.bhh1[1024 + col]);
        stcf(&p.gh1[(size_t)row * 3072 + 2048 + col], c2[r] + p.bhh1[2048 + col]);
      }
    }
    gbar(p.bar, epoch, b);
  }

  // ======== epilogue: predsT (t,n,m) -> out (n,m,t) ========
  {
    float* trS = (float*)smem;  // weights dead; reuse LDS
    for (int g = b; g < 504; g += 256) {
      int p0 = g * 16;
      for (int t0 = 0; t0 < 448; t0 += 16) {
        int tc = tid >> 4, pp = tid & 15;
        trS[tc * 17 + pp] = p.predsT[(size_t)(t0 + tc) * 8064 + p0 + pp];
        __syncthreads();
        p.out[(size_t)(p0 + (tid >> 4)) * 448 + t0 + (tid & 15)] = trS[(tid & 15) * 17 + (tid >> 4)];
        __syncthreads();
      }
    }
  }
}

// ---------------- host ----------------

extern "C" void kernel_launch(void* const* d_in, const int* in_sizes, int n_in,
                              void* d_out, int out_size, void* d_ws, size_t ws_size,
                              hipStream_t stream) {
  Ptrs p;
  p.aud = (const float*)d_in[0];
  p.mo  = (const float*)d_in[1];
  p.lxm = (const float*)d_in[2];
  p.vid = (const int*)d_in[3];
  p.eps = (const float*)d_in[4];
  p.csi_w0 = (const float*)d_in[5];  p.csi_b0 = (const float*)d_in[6];
  p.csi_w1 = (const float*)d_in[7];  p.csi_b1 = (const float*)d_in[8];
  p.csi_w2 = (const float*)d_in[9];  p.csi_b2 = (const float*)d_in[10];
  p.spk  = (const float*)d_in[11];
  p.mu_w = (const float*)d_in[12];   p.mu_b = (const float*)d_in[13];
  p.lv_w = (const float*)d_in[14];   p.lv_b = (const float*)d_in[15];
  p.embW = (const float*)d_in[16];   p.embB = (const float*)d_in[17];
  p.wih0 = (const float*)d_in[18];   p.whh0 = (const float*)d_in[19];
  p.bih0 = (const float*)d_in[20];   p.bhh0 = (const float*)d_in[21];
  p.wih1 = (const float*)d_in[22];   p.whh1 = (const float*)d_in[23];
  p.bih1 = (const float*)d_in[24];   p.bhh1 = (const float*)d_in[25];
  p.ln_g = (const float*)d_in[26];   p.ln_b = (const float*)d_in[27];
  p.predW = (const float*)d_in[28];  p.predB = (const float*)d_in[29];
  p.out = (float*)d_out;

  char* ws = (char*)d_ws;
  size_t off = 0;
  auto al = [&](size_t bytes) -> void* {
    void* r = (void*)(ws + off);
    off += (bytes + 255) & ~(size_t)255;
    return r;
  };
  p.bar    = (unsigned*)al(1024);
  p.stats  = (float*)al(512);
  p.mu5    = (float*)al(640);
  p.lv5    = (float*)al(640);
  p.h0F    = (float*)al(262144);
  p.h1F    = (float*)al(262144);
  p.h0B    = (f16*)al(131072);
  p.h1B    = (f16*)al(131072);
  p.ineB   = (f16*)al(131072);
  p.gh0    = (float*)al(786432);
  p.gh1    = (float*)al(786432);
  p.x0     = (float*)al(262144);
  p.x1     = (float*)al(262144);
  p.predsT = (float*)al(14450688);
  p.xcat   = (f16*)al(22020096);
  p.whh0P  = (f16*)al(6291456);
  p.whh1P  = (f16*)al(6291456);
  p.wih0aP = (f16*)al(6291456);
  p.wih0bP = (f16*)al(2359296);
  p.wih1P  = (f16*)al(6291456);
  p.embWP  = (f16*)al(786432);
  p.predWP = (f16*)al(262144);

  k_init<<<1, 256, 0, stream>>>(p);

  k_pack<<<dim3(192, 32), 256, 0, stream>>>(p.whh0, p.whh0P, 1024, 0, 3072, 3072);
  k_pack<<<dim3(192, 32), 256, 0, stream>>>(p.whh1, p.whh1P, 1024, 0, 3072, 3072);
  k_pack<<<dim3(192, 32), 256, 0, stream>>>(p.wih0, p.wih0aP, 1024, 0, 3072, 3072);
  k_pack<<<dim3(192, 12), 256, 0, stream>>>(p.wih0, p.wih0bP, 382, 1024, 3072, 3072);
  k_pack<<<dim3(192, 32), 256, 0, stream>>>(p.wih1, p.wih1P, 1024, 0, 3072, 3072);
  k_pack<<<dim3(64, 12), 256, 0, stream>>>(p.embW, p.embWP, 382, 0, 1024, 1024);
  k_pack<<<dim3(8, 32), 256, 0, stream>>>(p.predW, p.predWP, 1024, 0, 126, 126);

  k_csi1<<<256, 256, 0, stream>>>(p);
  k_csi2<<<256, 256, 0, stream>>>(p);
  k_csi3<<<512, 256, 0, stream>>>(p);
  k_gh<<<1536, 256, 0, stream>>>(p);
  k_style1<<<1, 256, 0, stream>>>(p);
  k_style2<<<3584, 256, 0, stream>>>(p);
  k_aud<<<1792, 256, 0, stream>>>(p);
  k_lxm<<<10752, 256, 0, stream>>>(p);
  k_premo0<<<32, 256, 0, stream>>>(p);
  k_padz<<<224, 256, 0, stream>>>(p);

  k_scan<<<256, 256, LDS_BYTES, stream>>>(p);

  (void)in_sizes; (void)n_in; (void)out_size; (void)ws_size;
}

// Round 5
// 18901.558 us; speedup vs baseline: 4.7760x; 1.4314x over previous
//
#include <hip/hip_runtime.h>
#include <cmath>

typedef _Float16 f16;
typedef _Float16 f16x8 __attribute__((ext_vector_type(8)));
typedef float f32x4 __attribute__((ext_vector_type(4)));
typedef unsigned long long u64;

#define MFMA_F16(a,b,c) __builtin_amdgcn_mfma_f32_16x16x32_f16((a),(b),(c),0,0,0)
#define AGENT __HIP_MEMORY_SCOPE_AGENT

// N=64, A=128, MO=126, LX=96, H=1024, S=32, P=2, B=16, BL=32, T=448
#define TSTEPS 448
#define OFF_MU 3612672   // 64*126*448
#define OFF_LV 4530176   // + 64*32*448
#define LDS_BYTES 144384

// signal classes
#define S1 0   // ineB ready        (64 signalers)
#define S2 1   // h0B ready         (64)
#define S3 2   // h1B + part ready  (64)
#define S3B 3  // gh0(t+1) ready    (64)
#define S4 4   // xcat(t+1)/pred    (8)
#define S4G 5  // gh1(t+1) ready    (64)

struct Ptrs {
  const float *aud, *mo, *lxm, *eps;
  const int *vid;
  const float *csi_w0, *csi_b0, *csi_w1, *csi_b1, *csi_w2, *csi_b2;
  const float *spk, *mu_w, *mu_b, *lv_w, *lv_b;
  const float *embW, *embB;
  const float *wih0, *whh0, *bih0, *bhh0;
  const float *wih1, *whh1, *bih1, *bhh1;
  const float *ln_g, *ln_b, *predW, *predB;
  float *out;
  unsigned *bar;
  float *part, *mu5, *lv5, *h0F, *h1F;
  f16 *h0B, *h1B, *ineB, *xcat;
  float *ghP0, *ghP1, *x0, *x1, *predsT;
  f16 *whh0P, *whh1P, *wih0aP, *wih0bP, *wih1P, *embWP, *predWP;
};

__device__ __forceinline__ float geluf(float x) {
  return 0.5f * x * (1.0f + erff(x * 0.7071067811865475f));
}
__device__ __forceinline__ float sigmf(float x) {
  return 1.0f / (1.0f + expf(-x));
}

// ---- coherent (cross-XCD) primitives: compiler-visible, batchable ----
__device__ __forceinline__ u64 ldc8(const void* p) {
  return __hip_atomic_load((const u64*)p, __ATOMIC_RELAXED, AGENT);
}
__device__ __forceinline__ void stc8(void* p, u64 v) {
  __hip_atomic_store((u64*)p, v, __ATOMIC_RELAXED, AGENT);
}
__device__ __forceinline__ void stcf(float* p, float v) {
  __hip_atomic_store(p, v, __ATOMIC_RELAXED, AGENT);
}
__device__ __forceinline__ f16x8 toH(u64 a, u64 b) {
  union { u64 u[2]; f16x8 h; } r; r.u[0] = a; r.u[1] = b; return r.h;
}
__device__ __forceinline__ f32x4 toF(u64 a, u64 b) {
  union { u64 u[2]; f32x4 f; } r; r.u[0] = a; r.u[1] = b; return r.f;
}
__device__ __forceinline__ u64 packF2(float a, float b) {
  union { float f[2]; u64 u; } r; r.f[0] = a; r.f[1] = b; return r.u;
}
// pack (v, lane^1's v) into 2 f16 and store 4B coherently from even lanes
__device__ __forceinline__ void st_pair(f16* base, float v, int lm, bool pred) {
  float vn = __shfl_xor(v, 1);
  if (!(lm & 1) && pred) {
    union { f16 h[2]; unsigned u; } pk;
    pk.h[0] = (f16)v; pk.h[1] = (f16)vn;
    __hip_atomic_store((unsigned*)base, pk.u, __ATOMIC_RELAXED, AGENT);
  }
}

// ---------------- prologue kernels ----------------

__global__ void k_init(Ptrs p) {
  int gid = blockIdx.x * 256 + threadIdx.x;
  if (gid < 2048) p.bar[gid] = 0u;
}

__global__ void k_pack(const float* __restrict__ src, f16* __restrict__ dst,
                       int K, int rowOff, int realN, int ldN) {
  int ct = blockIdx.x, kt = blockIdx.y;
  int e = threadIdx.x * 2;
  int l = e >> 3, i = e & 7;
  int k = kt * 32 + (l >> 4) * 8 + i;
  int col = ct * 16 + (l & 15);
  f16 v0 = (f16)0.f, v1 = (f16)0.f;
  if (k < K && col < realN)     v0 = (f16)src[(size_t)(rowOff + k) * ldN + col];
  if (k + 1 < K && col < realN) v1 = (f16)src[(size_t)(rowOff + k + 1) * ldN + col];
  size_t o = ((size_t)ct * gridDim.y + kt) * 512 + e;
  dst[o] = v0; dst[o + 1] = v1;
}

__global__ void k_csi1(Ptrs p) {
  int gid = blockIdx.x * 256 + threadIdx.x;  // 65536
  int n = gid >> 10, c = gid & 1023;
  float acc = p.csi_b0[c];
  const float* w = p.csi_w0 + c;
  for (int k = 0; k < 126; k++) acc += p.mo[((size_t)(n * 126 + k)) * 512 + 31] * w[(size_t)k * 1024];
  for (int k = 0; k < 96; k++)  acc += p.lxm[(size_t)(n * 96 + k) * 16] * w[(size_t)(126 + k) * 1024];
  p.x0[gid] = geluf(acc);
}

__global__ void k_csi2(Ptrs p) {
  int gid = blockIdx.x * 256 + threadIdx.x;
  int n = gid >> 10, c = gid & 1023;
  float acc = p.csi_b1[c];
  const float* w = p.csi_w1 + c;
  const float* x = p.x0 + (size_t)n * 1024;
  for (int k = 0; k < 1024; k++) acc += x[k] * w[(size_t)k * 1024];
  p.x1[gid] = geluf(acc);
}

__global__ void k_csi3(Ptrs p) {
  int gid = blockIdx.x * 256 + threadIdx.x;  // 131072
  int n = gid >> 11, c2 = gid & 2047;
  float acc = p.csi_b2[c2];
  const float* w = p.csi_w2 + c2;
  const float* x = p.x1 + (size_t)n * 1024;
  for (int k = 0; k < 1024; k++) acc += x[k] * w[(size_t)k * 2048];
  if (c2 < 1024) { p.h0F[n * 1024 + c2] = acc; p.h0B[n * 1024 + c2] = (f16)acc; }
  else           { p.h1F[n * 1024 + c2 - 1024] = acc; p.h1B[n * 1024 + c2 - 1024] = (f16)acc; }
}

// initial gh0/gh1 for t=0, packed per-consumer-lane records:
// ghP[((ct*16+lm)*16 + w*4+lq)*16 + g*4 + r], row = w*16+lq*4+r, col = g*1024 + ct*16+lm
__global__ void k_gh(Ptrs p) {
  int gid = blockIdx.x * 256 + threadIdx.x;  // 393216
  int which = gid >= 196608;
  int g2 = which ? gid - 196608 : gid;
  int n = g2 / 3072, c = g2 % 3072;
  const float* h = which ? p.h1F : p.h0F;
  const float* W = which ? p.whh1 : p.whh0;
  const float* bb = which ? p.bhh1 : p.bhh0;
  float acc = bb[c];
  const float* hr = h + (size_t)n * 1024;
  for (int k = 0; k < 1024; k++) acc += hr[k] * W[(size_t)k * 3072 + c];
  int g = c >> 10, col = c & 1023;
  int ct = col >> 4, lm = col & 15, w = n >> 4, lq = (n >> 2) & 3, r = n & 3;
  float* dst = which ? p.ghP1 : p.ghP0;
  dst[((size_t)((ct * 16 + lm) * 16 + w * 4 + lq)) * 16 + g * 4 + r] = acc;
}

__global__ void k_style1(Ptrs p) {
  int tid = threadIdx.x;
  if (tid < 160) {
    int v = tid >> 5, s = tid & 31;
    float m = p.mu_b[s], lv = p.lv_b[s];
    for (int k = 0; k < 32; k++) {
      float z = p.spk[v * 32 + k];
      m += z * p.mu_w[k * 32 + s];
      lv += z * p.lv_w[k * 32 + s];
    }
    p.mu5[v * 32 + s] = m; p.lv5[v * 32 + s] = lv;
  }
}

__global__ void k_style2(Ptrs p) {
  int gid = blockIdx.x * 256 + threadIdx.x;  // 917504
  int t = gid % 448;
  int rr = gid / 448;
  int s = rr & 31, n = rr >> 5;
  int v = p.vid[n * 16 + (t >> 5) + 1];
  float mu = p.mu5[v * 32 + s], lv = p.lv5[v * 32 + s];
  float e = p.eps[((size_t)t * 64 + n) * 32 + s];
  float st = mu + e * expf(0.5f * lv);
  p.out[OFF_MU + ((size_t)n * 32 + s) * 448 + t] = mu;
  p.out[OFF_LV + ((size_t)n * 32 + s) * 448 + t] = lv;
  p.xcat[((size_t)t * 64 + n) * 384 + 350 + s] = (f16)st;
}

__global__ void k_aud(Ptrs p) {
  __shared__ float tile[32][65];
  int bid = blockIdx.x;  // 64*4*7
  int n = bid / 28, rem = bid % 28;
  int a0 = (rem / 7) * 32, t0 = (rem % 7) * 64;
  int tid = threadIdx.x;
  for (int i = tid; i < 2048; i += 256) {
    int ai = i >> 6, tj = i & 63;
    tile[ai][tj] = p.aud[((size_t)n * 128 + a0 + ai) * 448 + t0 + tj];
  }
  __syncthreads();
  for (int i = tid; i < 2048; i += 256) {
    int tj = i >> 5, ai = i & 31;
    p.xcat[((size_t)(t0 + tj) * 64 + n) * 384 + 126 + a0 + ai] = (f16)tile[ai][tj];
  }
}

__global__ void k_lxm(Ptrs p) {
  int gid = blockIdx.x * 256 + threadIdx.x;  // 2752512
  int l_ = gid % 96;
  int r = gid / 96;
  int n = r & 63, t = r >> 6;
  int tb = (t >> 5) + 1;
  p.xcat[((size_t)t * 64 + n) * 384 + 254 + l_] = (f16)p.lxm[((size_t)n * 96 + l_) * 16 + tb];
}

__global__ void k_premo0(Ptrs p) {
  int gid = blockIdx.x * 256 + threadIdx.x;
  if (gid < 8064) {
    int n = gid / 126, m = gid % 126;
    p.xcat[(size_t)n * 384 + m] = (f16)p.mo[((size_t)n * 126 + m) * 512 + 31];
  }
}

__global__ void k_padz(Ptrs p) {
  int gid = blockIdx.x * 256 + threadIdx.x;  // 57344
  int t = gid >> 7, rem = gid & 127;
  int n = rem >> 1, c = 382 + (rem & 1);
  p.xcat[((size_t)t * 64 + n) * 384 + c] = (f16)0.f;
}

// ---------------- persistent scan kernel ----------------

__device__ __forceinline__ void sigc(unsigned* bar, int cls, int b) {
  asm volatile("s_waitcnt vmcnt(0)" ::: "memory");
  __syncthreads();
  if (threadIdx.x == 0)
    __hip_atomic_fetch_add(&bar[(cls * 8 + (b & 7)) * 32], 1u, __ATOMIC_RELAXED, AGENT);
}
__device__ __forceinline__ void waitc(unsigned* bar, int cls, unsigned tgt) {
  if (threadIdx.x < 8) {
    while (__hip_atomic_load(&bar[(cls * 8 + threadIdx.x) * 32], __ATOMIC_RELAXED, AGENT) < tgt)
      __builtin_amdgcn_s_sleep(1);
  }
  __syncthreads();
}
__device__ __forceinline__ void waitc2(unsigned* bar, int cA, unsigned tA, int cB, unsigned tB) {
  if (threadIdx.x < 16) {
    int cls = (threadIdx.x < 8) ? cA : cB;
    unsigned tgt = (threadIdx.x < 8) ? tA : tB;
    int sub = threadIdx.x & 7;
    while (__hip_atomic_load(&bar[(cls * 8 + sub) * 32], __ATOMIC_RELAXED, AGENT) < tgt)
      __builtin_amdgcn_s_sleep(1);
  }
  __syncthreads();
}

// pipelined 3-gate GEMM: A row coherent (batched u64 loads, double-buffered),
// weights LDS-resident at L+{0,16384,32768} (f16 offsets)
__device__ __forceinline__ void gemm3(const f16* aRow, const f16* L, int l,
                                      f32x4& A0, f32x4& A1, f32x4& A2) {
  const f16* w0 = L + l * 8;
  u64 ua[16], ub[16];
  #pragma unroll
  for (int j = 0; j < 8; j++) { ua[2*j] = ldc8(aRow + j * 32); ua[2*j+1] = ldc8(aRow + j * 32 + 4); }
  #pragma unroll
  for (int j = 0; j < 8; j++) { ub[2*j] = ldc8(aRow + 256 + j * 32); ub[2*j+1] = ldc8(aRow + 256 + j * 32 + 4); }
  #pragma unroll
  for (int j = 0; j < 8; j++) {
    f16x8 av = toH(ua[2*j], ua[2*j+1]);
    A0 = MFMA_F16(av, *(const f16x8*)(w0 + j * 512), A0);
    A1 = MFMA_F16(av, *(const f16x8*)(w0 + 16384 + j * 512), A1);
    A2 = MFMA_F16(av, *(const f16x8*)(w0 + 32768 + j * 512), A2);
  }
  #pragma unroll
  for (int j = 0; j < 8; j++) { ua[2*j] = ldc8(aRow + 512 + j * 32); ua[2*j+1] = ldc8(aRow + 512 + j * 32 + 4); }
  #pragma unroll
  for (int j = 0; j < 8; j++) {
    f16x8 av = toH(ub[2*j], ub[2*j+1]);
    int kt = 8 + j;
    A0 = MFMA_F16(av, *(const f16x8*)(w0 + kt * 512), A0);
    A1 = MFMA_F16(av, *(const f16x8*)(w0 + 16384 + kt * 512), A1);
    A2 = MFMA_F16(av, *(const f16x8*)(w0 + 32768 + kt * 512), A2);
  }
  #pragma unroll
  for (int j = 0; j < 8; j++) { ub[2*j] = ldc8(aRow + 768 + j * 32); ub[2*j+1] = ldc8(aRow + 768 + j * 32 + 4); }
  #pragma unroll
  for (int j = 0; j < 8; j++) {
    f16x8 av = toH(ua[2*j], ua[2*j+1]);
    int kt = 16 + j;
    A0 = MFMA_F16(av, *(const f16x8*)(w0 + kt * 512), A0);
    A1 = MFMA_F16(av, *(const f16x8*)(w0 + 16384 + kt * 512), A1);
    A2 = MFMA_F16(av, *(const f16x8*)(w0 + 32768 + kt * 512), A2);
  }
  #pragma unroll
  for (int j = 0; j < 8; j++) {
    f16x8 av = toH(ub[2*j], ub[2*j+1]);
    int kt = 24 + j;
    A0 = MFMA_F16(av, *(const f16x8*)(w0 + kt * 512), A0);
    A1 = MFMA_F16(av, *(const f16x8*)(w0 + 16384 + kt * 512), A1);
    A2 = MFMA_F16(av, *(const f16x8*)(w0 + 32768 + kt * 512), A2);
  }
}

__global__ __launch_bounds__(256, 1) void k_scan(Ptrs p) {
  extern __shared__ char smem[];
  f16* L = (f16*)smem;
  const int b = blockIdx.x, tid = threadIdx.x;
  const int w = tid >> 6, l = tid & 63;
  const int lm = l & 15, lq = l >> 4;

  // ---- one-time: stage weights into LDS (resident), preload biases ----
  {
    auto cp = [&](int dstF16, const f16* src, int nF16) {
      uint4* d = (uint4*)smem + (dstF16 >> 3);
      const uint4* s = (const uint4*)src;
      for (int i = tid; i < (nF16 >> 3); i += 256) d[i] = s[i];
    };
    if (b < 64) {
      cp(0,     p.wih0aP + (size_t)b * 16384, 16384);
      cp(16384, p.wih0aP + (size_t)(64 + b) * 16384, 16384);
      cp(32768, p.wih0aP + (size_t)(128 + b) * 16384, 16384);
      cp(49152, p.wih0bP + (size_t)b * 6144, 6144);
      cp(55296, p.wih0bP + (size_t)(64 + b) * 6144, 6144);
      cp(61440, p.wih0bP + (size_t)(128 + b) * 6144, 6144);
    } else if (b < 128) {
      int cb = b - 64;
      cp(0,     p.wih1P + (size_t)cb * 16384, 16384);
      cp(16384, p.wih1P + (size_t)(64 + cb) * 16384, 16384);
      cp(32768, p.wih1P + (size_t)(128 + cb) * 16384, 16384);
      cp(49152, p.embWP + (size_t)cb * 6144, 6144);
    } else if (b < 192) {
      int i = b - 128;
      cp(0,     p.whh0P + (size_t)i * 16384, 16384);
      cp(16384, p.whh0P + (size_t)(64 + i) * 16384, 16384);
      cp(32768, p.whh0P + (size_t)(128 + i) * 16384, 16384);
      if (i < 8) {
        cp(49152, p.predWP + (size_t)i * 16384, 16384);
        float* lnS = (float*)(smem + 131072);
        for (int i2 = tid; i2 < 1024; i2 += 256) {
          lnS[i2] = p.ln_g[i2];
          lnS[1024 + i2] = p.ln_b[i2];
        }
      }
    } else {
      int i = b - 192;
      cp(0,     p.whh1P + (size_t)i * 16384, 16384);
      cp(16384, p.whh1P + (size_t)(64 + i) * 16384, 16384);
      cp(32768, p.whh1P + (size_t)(128 + i) * 16384, 16384);
    }
  }
  // per-lane constant biases
  float b0r = 0.f, b1r = 0.f, b2r = 0.f, ebr = 0.f;
  if (b < 64) {
    int col = b * 16 + lm;
    b0r = p.bih0[col]; b1r = p.bih0[1024 + col]; b2r = p.bih0[2048 + col];
  } else if (b < 128) {
    int col = (b - 64) * 16 + lm;
    b0r = p.bih1[col]; b1r = p.bih1[1024 + col]; b2r = p.bih1[2048 + col];
    ebr = p.embB[col];
  } else if (b < 192) {
    int col = (b - 128) * 16 + lm;
    b0r = p.bhh0[col]; b1r = p.bhh0[1024 + col]; b2r = p.bhh0[2048 + col];
    if (b < 136) ebr = (col < 126) ? p.predB[col] : 0.f;
  } else {
    int col = (b - 192) * 16 + lm;
    b0r = p.bhh1[col]; b1r = p.bhh1[1024 + col]; b2r = p.bhh1[2048 + col];
  }
  __syncthreads();

  unsigned* bar = p.bar;

  for (unsigned t = 0; t < TSTEPS; t++) {
    const f16* xc = p.xcat + (size_t)t * 24576;

    if (b < 64) {
      // ================= BB: P1 (gip in regs) then B (h0n) =================
      if (t) waitc(bar, S4, t);
      f32x4 gip0, gip1, gip2;
      {
        const f16* aB = xc + (w * 16 + lm) * 384 + lq * 8;
        u64 up[8];
        #pragma unroll
        for (int kt = 0; kt < 4; kt++) { up[2*kt] = ldc8(aB + kt * 32); up[2*kt+1] = ldc8(aB + kt * 32 + 4); }
        f16x8 af[12];
        #pragma unroll
        for (int kt = 4; kt < 12; kt++) af[kt] = *(const f16x8*)(aB + kt * 32);
        #pragma unroll
        for (int kt = 0; kt < 4; kt++) af[kt] = toH(up[2*kt], up[2*kt+1]);
        f32x4 a0 = {0,0,0,0}, a1 = {0,0,0,0}, a2 = {0,0,0,0};
        const f16* wl = L + 49152 + l * 8;
        #pragma unroll
        for (int kt = 0; kt < 12; kt++) {
          a0 = MFMA_F16(af[kt], *(const f16x8*)(wl + kt * 512), a0);
          a1 = MFMA_F16(af[kt], *(const f16x8*)(wl + 6144 + kt * 512), a1);
          a2 = MFMA_F16(af[kt], *(const f16x8*)(wl + 12288 + kt * 512), a2);
        }
        #pragma unroll
        for (int r = 0; r < 4; r++) {
          gip0[r] = a0[r] + b0r; gip1[r] = a1[r] + b1r; gip2[r] = a2[r] + b2r;
        }
      }
      waitc2(bar, S1, 8 * (t + 1), S3B, 8 * t);
      {
        const float* rec = p.ghP0 + ((size_t)((b * 16 + lm) * 16 + w * 4 + lq)) * 16;
        u64 r0 = ldc8(rec), r1 = ldc8(rec + 2), r2 = ldc8(rec + 4);
        u64 r3 = ldc8(rec + 6), r4 = ldc8(rec + 8), r5 = ldc8(rec + 10);
        f32x4 A0 = {0,0,0,0}, A1 = {0,0,0,0}, A2 = {0,0,0,0};
        gemm3(p.ineB + (w * 16 + lm) * 1024 + lq * 8, L, l, A0, A1, A2);
        f32x4 g0 = toF(r0, r1), g1 = toF(r2, r3), g2 = toF(r4, r5);
        int col = b * 16 + lm;
        #pragma unroll
        for (int r = 0; r < 4; r++) {
          int row = w * 16 + lq * 4 + r;
          float r_ = sigmf(A0[r] + gip0[r] + g0[r]);
          float z_ = sigmf(A1[r] + gip1[r] + g1[r]);
          float n_ = tanhf(A2[r] + gip2[r] + r_ * g2[r]);
          float* hf = p.h0F + (size_t)row * 1024 + col;
          float hn = (1.f - z_) * n_ + z_ * (*hf);
          *hf = hn;
          st_pair(p.h0B + (size_t)row * 1024 + col, hn, lm, true);
        }
      }
      sigc(bar, S2, b);
    } else if (b < 128) {
      // ================= CB: P1 (ine) then C (h1n) =================
      int cb = b - 64;
      int col = cb * 16 + lm;
      if (t) waitc(bar, S4, t);
      {
        const f16* aB = xc + (w * 16 + lm) * 384 + lq * 8;
        u64 up[8];
        #pragma unroll
        for (int kt = 0; kt < 4; kt++) { up[2*kt] = ldc8(aB + kt * 32); up[2*kt+1] = ldc8(aB + kt * 32 + 4); }
        f16x8 af[12];
        #pragma unroll
        for (int kt = 4; kt < 12; kt++) af[kt] = *(const f16x8*)(aB + kt * 32);
        #pragma unroll
        for (int kt = 0; kt < 4; kt++) af[kt] = toH(up[2*kt], up[2*kt+1]);
        f32x4 acc = {0,0,0,0};
        const f16* wl = L + 49152 + l * 8;
        #pragma unroll
        for (int kt = 0; kt < 12; kt++)
          acc = MFMA_F16(af[kt], *(const f16x8*)(wl + kt * 512), acc);
        #pragma unroll
        for (int r = 0; r < 4; r++) {
          int row = w * 16 + lq * 4 + r;
          float v = geluf(acc[r] + ebr);
          st_pair(p.ineB + (size_t)row * 1024 + col, v, lm, true);
        }
      }
      sigc(bar, S1, b);
      waitc2(bar, S2, 8 * (t + 1), S4G, 8 * t);
      {
        const float* rec = p.ghP1 + ((size_t)((cb * 16 + lm) * 16 + w * 4 + lq)) * 16;
        u64 r0 = ldc8(rec), r1 = ldc8(rec + 2), r2 = ldc8(rec + 4);
        u64 r3 = ldc8(rec + 6), r4 = ldc8(rec + 8), r5 = ldc8(rec + 10);
        f32x4 A0 = {0,0,0,0}, A1 = {0,0,0,0}, A2 = {0,0,0,0};
        gemm3(p.h0B + (w * 16 + lm) * 1024 + lq * 8, L, l, A0, A1, A2);
        f32x4 g0 = toF(r0, r1), g1 = toF(r2, r3), g2 = toF(r4, r5);
        float sv[4], sq[4];
        #pragma unroll
        for (int r = 0; r < 4; r++) {
          int row = w * 16 + lq * 4 + r;
          float r_ = sigmf(A0[r] + b0r + g0[r]);
          float z_ = sigmf(A1[r] + b1r + g1[r]);
          float n_ = tanhf(A2[r] + b2r + r_ * g2[r]);
          float* hf = p.h1F + (size_t)row * 1024 + col;
          float hn = (1.f - z_) * n_ + z_ * (*hf);
          *hf = hn;
          st_pair(p.h1B + (size_t)row * 1024 + col, hn, lm, true);
          sv[r] = hn; sq[r] = hn * hn;
        }
        #pragma unroll
        for (int m = 1; m < 16; m <<= 1) {
          #pragma unroll
          for (int r = 0; r < 4; r++) { sv[r] += __shfl_xor(sv[r], m); sq[r] += __shfl_xor(sq[r], m); }
        }
        if (lm == 0) {
          #pragma unroll
          for (int r = 0; r < 4; r++) {
            int row = w * 16 + lq * 4 + r;
            stc8(&p.part[cb * 128 + row * 2], packF2(sv[r], sq[r]));
          }
        }
      }
      sigc(bar, S3, b);
    } else if (b < 192) {
      // ================= GH0: gh0(t+1); blocks 128..135 also pred =================
      int i = b - 128;
      waitc(bar, S2, 8 * (t + 1));
      {
        f32x4 A0 = {0,0,0,0}, A1 = {0,0,0,0}, A2 = {0,0,0,0};
        gemm3(p.h0B + (w * 16 + lm) * 1024 + lq * 8, L, l, A0, A1, A2);
        float* rec = p.ghP0 + ((size_t)((i * 16 + lm) * 16 + w * 4 + lq)) * 16;
        stc8(rec,      packF2(A0[0] + b0r, A0[1] + b0r));
        stc8(rec + 2,  packF2(A0[2] + b0r, A0[3] + b0r));
        stc8(rec + 4,  packF2(A1[0] + b1r, A1[1] + b1r));
        stc8(rec + 6,  packF2(A1[2] + b1r, A1[3] + b1r));
        stc8(rec + 8,  packF2(A2[0] + b2r, A2[1] + b2r));
        stc8(rec + 10, packF2(A2[2] + b2r, A2[3] + b2r));
      }
      sigc(bar, S3B, b);
      if (i < 8) {
        waitc(bar, S3, 8 * (t + 1));
        float* lnS = (float*)(smem + 131072);
        float* redS = (float*)(smem + 139264);
        float* statsS = (float*)(smem + 143360);
        {  // reduce part: 64 blocks x 128 entries
          int gg = tid >> 5, j4 = tid & 31;
          u64 pu[16];
          #pragma unroll
          for (int c = 0; c < 8; c++) {
            const float* q = p.part + ((gg * 8 + c) * 128 + j4 * 4);
            pu[2*c] = ldc8(q); pu[2*c+1] = ldc8(q + 2);
          }
          f32x4 s = {0,0,0,0};
          #pragma unroll
          for (int c = 0; c < 8; c++) s += toF(pu[2*c], pu[2*c+1]);
          *(f32x4*)(redS + gg * 128 + j4 * 4) = s;
        }
        __syncthreads();
        if (tid < 128) {
          float v = 0.f;
          #pragma unroll
          for (int gg = 0; gg < 8; gg++) v += redS[gg * 128 + tid];
          statsS[tid] = v;
        }
        __syncthreads();
        int myrow = w * 16 + lm;
        float mean = statsS[myrow * 2] * 0.0009765625f;
        float var  = statsS[myrow * 2 + 1] * 0.0009765625f - mean * mean;
        float rstd = rsqrtf(var + 1e-5f);
        f32x4 acc = {0,0,0,0};
        const f16* hB = p.h1B + (size_t)myrow * 1024 + lq * 8;
        const f16* wp = L + 49152 + l * 8;
        u64 ua[16], ub[16];
        #pragma unroll
        for (int j = 0; j < 8; j++) { ua[2*j] = ldc8(hB + j * 32); ua[2*j+1] = ldc8(hB + j * 32 + 4); }
        #pragma unroll
        for (int j = 0; j < 8; j++) { ub[2*j] = ldc8(hB + 256 + j * 32); ub[2*j+1] = ldc8(hB + 256 + j * 32 + 4); }
        auto compP = [&](u64* cur, int g) {
          #pragma unroll
          for (int j = 0; j < 8; j++) {
            int kt = g * 8 + j, k0 = kt * 32 + lq * 8;
            f16x8 hv = toH(cur[2*j], cur[2*j+1]);
            f16x8 af;
            #pragma unroll
            for (int e = 0; e < 8; e++)
              af[e] = (f16)(((float)hv[e] - mean) * rstd * lnS[k0 + e] + lnS[1024 + k0 + e]);
            acc = MFMA_F16(af, *(const f16x8*)(wp + kt * 512), acc);
          }
        };
        compP(ua, 0);
        #pragma unroll
        for (int j = 0; j < 8; j++) { ua[2*j] = ldc8(hB + 512 + j * 32); ua[2*j+1] = ldc8(hB + 512 + j * 32 + 4); }
        compP(ub, 1);
        #pragma unroll
        for (int j = 0; j < 8; j++) { ub[2*j] = ldc8(hB + 768 + j * 32); ub[2*j+1] = ldc8(hB + 768 + j * 32 + 4); }
        compP(ua, 2);
        compP(ub, 3);
        int col = i * 16 + lm;
        #pragma unroll
        for (int r = 0; r < 4; r++) {
          int row = w * 16 + lq * 4 + r;
          float v = acc[r] + ebr;
          if (col < 126) stcf(&p.predsT[(size_t)t * 8064 + row * 126 + col], v);
          st_pair(p.xcat + (size_t)(t + 1) * 24576 + row * 384 + col, v, lm,
                  col < 126 && t < 447);
        }
        sigc(bar, S4, b);
      }
    } else {
      // ================= GH1: gh1(t+1) =================
      int i = b - 192;
      waitc(bar, S3, 8 * (t + 1));
      {
        f32x4 A0 = {0,0,0,0}, A1 = {0,0,0,0}, A2 = {0,0,0,0};
        gemm3(p.h1B + (w * 16 + lm) * 1024 + lq * 8, L, l, A0, A1, A2);
        float* rec = p.ghP1 + ((size_t)((i * 16 + lm) * 16 + w * 4 + lq)) * 16;
        stc8(rec,      packF2(A0[0] + b0r, A0[1] + b0r));
        stc8(rec + 2,  packF2(A0[2] + b0r, A0[3] + b0r));
        stc8(rec + 4,  packF2(A1[0] + b1r, A1[1] + b1r));
        stc8(rec + 6,  packF2(A1[2] + b1r, A1[3] + b1r));
        stc8(rec + 8,  packF2(A2[0] + b2r, A2[1] + b2r));
        stc8(rec + 10, packF2(A2[2] + b2r, A2[3] + b2r));
      }
      sigc(bar, S4G, b);
    }
  }

  // ======== epilogue: predsT (t,n,m) -> out (n,m,t) ========
  waitc(bar, S4, TSTEPS);
  {
    float* trS = (float*)smem;
    for (int g = b; g < 504; g += 256) {
      int p0 = g * 16;
      for (int t0 = 0; t0 < 448; t0 += 16) {
        int tc = tid >> 4, pp = tid & 15;
        trS[tc * 17 + pp] = p.predsT[(size_t)(t0 + tc) * 8064 + p0 + pp];
        __syncthreads();
        p.out[(size_t)(p0 + (tid >> 4)) * 448 + t0 + (tid & 15)] = trS[(tid & 15) * 17 + (tid >> 4)];
        __syncthreads();
      }
    }
  }
}

// ---------------- host ----------------

extern "C" void kernel_launch(void* const* d_in, const int* in_sizes, int n_in,
                              void* d_out, int out_size, void* d_ws, size_t ws_size,
                              hipStream_t stream) {
  Ptrs p;
  p.aud = (const float*)d_in[0];
  p.mo  = (const float*)d_in[1];
  p.lxm = (const float*)d_in[2];
  p.vid = (const int*)d_in[3];
  p.eps = (const float*)d_in[4];
  p.csi_w0 = (const float*)d_in[5];  p.csi_b0 = (const float*)d_in[6];
  p.csi_w1 = (const float*)d_in[7];  p.csi_b1 = (const float*)d_in[8];
  p.csi_w2 = (const float*)d_in[9];  p.csi_b2 = (const float*)d_in[10];
  p.spk  = (const float*)d_in[11];
  p.mu_w = (const float*)d_in[12];   p.mu_b = (const float*)d_in[13];
  p.lv_w = (const float*)d_in[14];   p.lv_b = (const float*)d_in[15];
  p.embW = (const float*)d_in[16];   p.embB = (const float*)d_in[17];
  p.wih0 = (const float*)d_in[18];   p.whh0 = (const float*)d_in[19];
  p.bih0 = (const float*)d_in[20];   p.bhh0 = (const float*)d_in[21];
  p.wih1 = (const float*)d_in[22];   p.whh1 = (const float*)d_in[23];
  p.bih1 = (const float*)d_in[24];   p.bhh1 = (const float*)d_in[25];
  p.ln_g = (const float*)d_in[26];   p.ln_b = (const float*)d_in[27];
  p.predW = (const float*)d_in[28];  p.predB = (const float*)d_in[29];
  p.out = (float*)d_out;

  char* ws = (char*)d_ws;
  size_t off = 0;
  auto al = [&](size_t bytes) -> void* {
    void* r = (void*)(ws + off);
    off += (bytes + 255) & ~(size_t)255;
    return r;
  };
  p.bar    = (unsigned*)al(8192);
  p.part   = (float*)al(32768);
  p.mu5    = (float*)al(640);
  p.lv5    = (float*)al(640);
  p.h0F    = (float*)al(262144);
  p.h1F    = (float*)al(262144);
  p.h0B    = (f16*)al(131072);
  p.h1B    = (f16*)al(131072);
  p.ineB   = (f16*)al(131072);
  p.ghP0   = (float*)al(1048576);
  p.ghP1   = (float*)al(1048576);
  p.x0     = (float*)al(262144);
  p.x1     = (float*)al(262144);
  p.predsT = (float*)al(14450688);
  p.xcat   = (f16*)al(22020096);
  p.whh0P  = (f16*)al(6291456);
  p.whh1P  = (f16*)al(6291456);
  p.wih0aP = (f16*)al(6291456);
  p.wih0bP = (f16*)al(2359296);
  p.wih1P  = (f16*)al(6291456);
  p.embWP  = (f16*)al(786432);
  p.predWP = (f16*)al(262144);

  k_init<<<8, 256, 0, stream>>>(p);

  k_pack<<<dim3(192, 32), 256, 0, stream>>>(p.whh0, p.whh0P, 1024, 0, 3072, 3072);
  k_pack<<<dim3(192, 32), 256, 0, stream>>>(p.whh1, p.whh1P, 1024, 0, 3072, 3072);
  k_pack<<<dim3(192, 32), 256, 0, stream>>>(p.wih0, p.wih0aP, 1024, 0, 3072, 3072);
  k_pack<<<dim3(192, 12), 256, 0, stream>>>(p.wih0, p.wih0bP, 382, 1024, 3072, 3072);
  k_pack<<<dim3(192, 32), 256, 0, stream>>>(p.wih1, p.wih1P, 1024, 0, 3072, 3072);
  k_pack<<<dim3(64, 12), 256, 0, stream>>>(p.embW, p.embWP, 382, 0, 1024, 1024);
  k_pack<<<dim3(8, 32), 256, 0, stream>>>(p.predW, p.predWP, 1024, 0, 126, 126);

  k_csi1<<<256, 256, 0, stream>>>(p);
  k_csi2<<<256, 256, 0, stream>>>(p);
  k_csi3<<<512, 256, 0, stream>>>(p);
  k_gh<<<1536, 256, 0, stream>>>(p);
  k_style1<<<1, 256, 0, stream>>>(p);
  k_style2<<<3584, 256, 0, stream>>>(p);
  k_aud<<<1792, 256, 0, stream>>>(p);
  k_lxm<<<10752, 256, 0, stream>>>(p);
  k_premo0<<<32, 256, 0, stream>>>(p);
  k_padz<<<224, 256, 0, stream>>>(p);

  k_scan<<<256, 256, LDS_BYTES, stream>>>(p);

  (void)in_sizes; (void)n_in; (void)out_size; (void)ws_size;
}

// Round 6
// 18450.960 us; speedup vs baseline: 4.8926x; 1.0244x over previous
//
#include <hip/hip_runtime.h>
#include <cmath>

typedef _Float16 f16;
typedef _Float16 f16x8 __attribute__((ext_vector_type(8)));
typedef float f32x4 __attribute__((ext_vector_type(4)));
typedef unsigned long long u64;

#define MFMA_F16(a,b,c) __builtin_amdgcn_mfma_f32_16x16x32_f16((a),(b),(c),0,0,0)
#define AGENT __HIP_MEMORY_SCOPE_AGENT

// N=64, A=128, MO=126, LX=96, H=1024, S=32, P=2, B=16, BL=32, T=448
#define TSTEPS 448
#define OFF_MU 3612672   // 64*126*448
#define OFF_LV 4530176   // + 64*32*448
#define LDS_BYTES 156160

// signal classes
#define S1 0   // ineB ready        (64 signalers)
#define S2 1   // h0B ready         (64)
#define S3 2   // h1B + part ready  (64)
#define S3B 3  // gh0(t+1) ready    (64)
#define S4 4   // xcat(t+1)/pred    (8)
#define S4G 5  // gh1(t+1) ready    (64)

struct Ptrs {
  const float *aud, *mo, *lxm, *eps;
  const int *vid;
  const float *csi_w0, *csi_b0, *csi_w1, *csi_b1, *csi_w2, *csi_b2;
  const float *spk, *mu_w, *mu_b, *lv_w, *lv_b;
  const float *embW, *embB;
  const float *wih0, *whh0, *bih0, *bhh0;
  const float *wih1, *whh1, *bih1, *bhh1;
  const float *ln_g, *ln_b, *predW, *predB;
  float *out;
  unsigned *bar;
  float *part, *mu5, *lv5, *h0F, *h1F;
  f16 *h0B, *h1B, *ineB, *xcat;
  float *ghP0, *ghP1, *x0, *x1, *predsT;
  f16 *whh0P, *whh1P, *wih0aP, *wih0bP, *wih1P, *embWP, *predWP;
};

__device__ __forceinline__ float geluf(float x) {
  return 0.5f * x * (1.0f + erff(x * 0.7071067811865475f));
}
__device__ __forceinline__ float sigmf(float x) {
  return 1.0f / (1.0f + expf(-x));
}

// ---- coherent (cross-XCD) primitives: compiler-visible, batchable ----
__device__ __forceinline__ u64 ldc8(const void* p) {
  return __hip_atomic_load((const u64*)p, __ATOMIC_RELAXED, AGENT);
}
__device__ __forceinline__ void stc8(void* p, u64 v) {
  __hip_atomic_store((u64*)p, v, __ATOMIC_RELAXED, AGENT);
}
__device__ __forceinline__ void stcf(float* p, float v) {
  __hip_atomic_store(p, v, __ATOMIC_RELAXED, AGENT);
}
__device__ __forceinline__ f16x8 toH(u64 a, u64 b) {
  union { u64 u[2]; f16x8 h; } r; r.u[0] = a; r.u[1] = b; return r.h;
}
__device__ __forceinline__ f32x4 toF(u64 a, u64 b) {
  union { u64 u[2]; f32x4 f; } r; r.u[0] = a; r.u[1] = b; return r.f;
}
__device__ __forceinline__ u64 packF2(float a, float b) {
  union { float f[2]; u64 u; } r; r.f[0] = a; r.f[1] = b; return r.u;
}
// pack (v, lane^1's v) into 2 f16 and store 4B coherently from even lanes
__device__ __forceinline__ void st_pair(f16* base, float v, int lm, bool pred) {
  float vn = __shfl_xor(v, 1);
  if (!(lm & 1) && pred) {
    union { f16 h[2]; unsigned u; } pk;
    pk.h[0] = (f16)v; pk.h[1] = (f16)vn;
    __hip_atomic_store((unsigned*)base, pk.u, __ATOMIC_RELAXED, AGENT);
  }
}

// ---------------- prologue kernels ----------------

__global__ void k_init(Ptrs p) {
  int gid = blockIdx.x * 256 + threadIdx.x;
  if (gid < 2048) p.bar[gid] = 0u;
}

__global__ void k_pack(const float* __restrict__ src, f16* __restrict__ dst,
                       int K, int rowOff, int realN, int ldN) {
  int ct = blockIdx.x, kt = blockIdx.y;
  int e = threadIdx.x * 2;
  int l = e >> 3, i = e & 7;
  int k = kt * 32 + (l >> 4) * 8 + i;
  int col = ct * 16 + (l & 15);
  f16 v0 = (f16)0.f, v1 = (f16)0.f;
  if (k < K && col < realN)     v0 = (f16)src[(size_t)(rowOff + k) * ldN + col];
  if (k + 1 < K && col < realN) v1 = (f16)src[(size_t)(rowOff + k + 1) * ldN + col];
  size_t o = ((size_t)ct * gridDim.y + kt) * 512 + e;
  dst[o] = v0; dst[o + 1] = v1;
}

__global__ void k_csi1(Ptrs p) {
  int gid = blockIdx.x * 256 + threadIdx.x;  // 65536
  int n = gid >> 10, c = gid & 1023;
  float acc = p.csi_b0[c];
  const float* w = p.csi_w0 + c;
  for (int k = 0; k < 126; k++) acc += p.mo[((size_t)(n * 126 + k)) * 512 + 31] * w[(size_t)k * 1024];
  for (int k = 0; k < 96; k++)  acc += p.lxm[(size_t)(n * 96 + k) * 16] * w[(size_t)(126 + k) * 1024];
  p.x0[gid] = geluf(acc);
}

__global__ void k_csi2(Ptrs p) {
  int gid = blockIdx.x * 256 + threadIdx.x;
  int n = gid >> 10, c = gid & 1023;
  float acc = p.csi_b1[c];
  const float* w = p.csi_w1 + c;
  const float* x = p.x0 + (size_t)n * 1024;
  for (int k = 0; k < 1024; k++) acc += x[k] * w[(size_t)k * 1024];
  p.x1[gid] = geluf(acc);
}

__global__ void k_csi3(Ptrs p) {
  int gid = blockIdx.x * 256 + threadIdx.x;  // 131072
  int n = gid >> 11, c2 = gid & 2047;
  float acc = p.csi_b2[c2];
  const float* w = p.csi_w2 + c2;
  const float* x = p.x1 + (size_t)n * 1024;
  for (int k = 0; k < 1024; k++) acc += x[k] * w[(size_t)k * 2048];
  if (c2 < 1024) { p.h0F[n * 1024 + c2] = acc; p.h0B[n * 1024 + c2] = (f16)acc; }
  else           { p.h1F[n * 1024 + c2 - 1024] = acc; p.h1B[n * 1024 + c2 - 1024] = (f16)acc; }
}

// initial gh0/gh1 for t=0, packed per-consumer-lane records:
// ghP[((ct*16+lm)*16 + w*4+lq)*16 + g*4 + r], row = w*16+lq*4+r, col = g*1024 + ct*16+lm
__global__ void k_gh(Ptrs p) {
  int gid = blockIdx.x * 256 + threadIdx.x;  // 393216
  int which = gid >= 196608;
  int g2 = which ? gid - 196608 : gid;
  int n = g2 / 3072, c = g2 % 3072;
  const float* h = which ? p.h1F : p.h0F;
  const float* W = which ? p.whh1 : p.whh0;
  const float* bb = which ? p.bhh1 : p.bhh0;
  float acc = bb[c];
  const float* hr = h + (size_t)n * 1024;
  for (int k = 0; k < 1024; k++) acc += hr[k] * W[(size_t)k * 3072 + c];
  int g = c >> 10, col = c & 1023;
  int ct = col >> 4, lm = col & 15, w = n >> 4, lq = (n >> 2) & 3, r = n & 3;
  float* dst = which ? p.ghP1 : p.ghP0;
  dst[((size_t)((ct * 16 + lm) * 16 + w * 4 + lq)) * 16 + g * 4 + r] = acc;
}

__global__ void k_style1(Ptrs p) {
  int tid = threadIdx.x;
  if (tid < 160) {
    int v = tid >> 5, s = tid & 31;
    float m = p.mu_b[s], lv = p.lv_b[s];
    for (int k = 0; k < 32; k++) {
      float z = p.spk[v * 32 + k];
      m += z * p.mu_w[k * 32 + s];
      lv += z * p.lv_w[k * 32 + s];
    }
    p.mu5[v * 32 + s] = m; p.lv5[v * 32 + s] = lv;
  }
}

__global__ void k_style2(Ptrs p) {
  int gid = blockIdx.x * 256 + threadIdx.x;  // 917504
  int t = gid % 448;
  int rr = gid / 448;
  int s = rr & 31, n = rr >> 5;
  int v = p.vid[n * 16 + (t >> 5) + 1];
  float mu = p.mu5[v * 32 + s], lv = p.lv5[v * 32 + s];
  float e = p.eps[((size_t)t * 64 + n) * 32 + s];
  float st = mu + e * expf(0.5f * lv);
  p.out[OFF_MU + ((size_t)n * 32 + s) * 448 + t] = mu;
  p.out[OFF_LV + ((size_t)n * 32 + s) * 448 + t] = lv;
  p.xcat[((size_t)t * 64 + n) * 384 + 350 + s] = (f16)st;
}

__global__ void k_aud(Ptrs p) {
  __shared__ float tile[32][65];
  int bid = blockIdx.x;  // 64*4*7
  int n = bid / 28, rem = bid % 28;
  int a0 = (rem / 7) * 32, t0 = (rem % 7) * 64;
  int tid = threadIdx.x;
  for (int i = tid; i < 2048; i += 256) {
    int ai = i >> 6, tj = i & 63;
    tile[ai][tj] = p.aud[((size_t)n * 128 + a0 + ai) * 448 + t0 + tj];
  }
  __syncthreads();
  for (int i = tid; i < 2048; i += 256) {
    int tj = i >> 5, ai = i & 31;
    p.xcat[((size_t)(t0 + tj) * 64 + n) * 384 + 126 + a0 + ai] = (f16)tile[ai][tj];
  }
}

__global__ void k_lxm(Ptrs p) {
  int gid = blockIdx.x * 256 + threadIdx.x;  // 2752512
  int l_ = gid % 96;
  int r = gid / 96;
  int n = r & 63, t = r >> 6;
  int tb = (t >> 5) + 1;
  p.xcat[((size_t)t * 64 + n) * 384 + 254 + l_] = (f16)p.lxm[((size_t)n * 96 + l_) * 16 + tb];
}

__global__ void k_premo0(Ptrs p) {
  int gid = blockIdx.x * 256 + threadIdx.x;
  if (gid < 8064) {
    int n = gid / 126, m = gid % 126;
    p.xcat[(size_t)n * 384 + m] = (f16)p.mo[((size_t)n * 126 + m) * 512 + 31];
  }
}

__global__ void k_padz(Ptrs p) {
  int gid = blockIdx.x * 256 + threadIdx.x;  // 57344
  int t = gid >> 7, rem = gid & 127;
  int n = rem >> 1, c = 382 + (rem & 1);
  p.xcat[((size_t)t * 64 + n) * 384 + c] = (f16)0.f;
}

// ---------------- persistent scan kernel ----------------

__device__ __forceinline__ void sigc(unsigned* bar, int cls, int b) {
  asm volatile("s_waitcnt vmcnt(0)" ::: "memory");
  __syncthreads();
  if (threadIdx.x == 0)
    __hip_atomic_fetch_add(&bar[(cls * 8 + (b & 7)) * 32], 1u, __ATOMIC_RELAXED, AGENT);
}
// busy-poll (no s_sleep): keeps clocks up and detection tight
__device__ __forceinline__ void waitc(unsigned* bar, int cls, unsigned tgt) {
  if (threadIdx.x < 8) {
    while (__hip_atomic_load(&bar[(cls * 8 + threadIdx.x) * 32], __ATOMIC_RELAXED, AGENT) < tgt) {}
  }
  __syncthreads();
}
__device__ __forceinline__ void waitc2(unsigned* bar, int cA, unsigned tA, int cB, unsigned tB) {
  if (threadIdx.x < 16) {
    int cls = (threadIdx.x < 8) ? cA : cB;
    unsigned tgt = (threadIdx.x < 8) ? tA : tB;
    int sub = threadIdx.x & 7;
    while (__hip_atomic_load(&bar[(cls * 8 + sub) * 32], __ATOMIC_RELAXED, AGENT) < tgt) {}
  }
  __syncthreads();
}

// pipelined 3-gate GEMM: A row coherent (batched u64 loads, double-buffered),
// weights LDS-resident at L+{0,16384,32768} (f16 offsets)
__device__ __forceinline__ void gemm3(const f16* aRow, const f16* L, int l,
                                      f32x4& A0, f32x4& A1, f32x4& A2) {
  const f16* w0 = L + l * 8;
  u64 ua[16], ub[16];
  #pragma unroll
  for (int j = 0; j < 8; j++) { ua[2*j] = ldc8(aRow + j * 32); ua[2*j+1] = ldc8(aRow + j * 32 + 4); }
  #pragma unroll
  for (int j = 0; j < 8; j++) { ub[2*j] = ldc8(aRow + 256 + j * 32); ub[2*j+1] = ldc8(aRow + 256 + j * 32 + 4); }
  #pragma unroll
  for (int j = 0; j < 8; j++) {
    f16x8 av = toH(ua[2*j], ua[2*j+1]);
    A0 = MFMA_F16(av, *(const f16x8*)(w0 + j * 512), A0);
    A1 = MFMA_F16(av, *(const f16x8*)(w0 + 16384 + j * 512), A1);
    A2 = MFMA_F16(av, *(const f16x8*)(w0 + 32768 + j * 512), A2);
  }
  #pragma unroll
  for (int j = 0; j < 8; j++) { ua[2*j] = ldc8(aRow + 512 + j * 32); ua[2*j+1] = ldc8(aRow + 512 + j * 32 + 4); }
  #pragma unroll
  for (int j = 0; j < 8; j++) {
    f16x8 av = toH(ub[2*j], ub[2*j+1]);
    int kt = 8 + j;
    A0 = MFMA_F16(av, *(const f16x8*)(w0 + kt * 512), A0);
    A1 = MFMA_F16(av, *(const f16x8*)(w0 + 16384 + kt * 512), A1);
    A2 = MFMA_F16(av, *(const f16x8*)(w0 + 32768 + kt * 512), A2);
  }
  #pragma unroll
  for (int j = 0; j < 8; j++) { ub[2*j] = ldc8(aRow + 768 + j * 32); ub[2*j+1] = ldc8(aRow + 768 + j * 32 + 4); }
  #pragma unroll
  for (int j = 0; j < 8; j++) {
    f16x8 av = toH(ua[2*j], ua[2*j+1]);
    int kt = 16 + j;
    A0 = MFMA_F16(av, *(const f16x8*)(w0 + kt * 512), A0);
    A1 = MFMA_F16(av, *(const f16x8*)(w0 + 16384 + kt * 512), A1);
    A2 = MFMA_F16(av, *(const f16x8*)(w0 + 32768 + kt * 512), A2);
  }
  #pragma unroll
  for (int j = 0; j < 8; j++) {
    f16x8 av = toH(ub[2*j], ub[2*j+1]);
    int kt = 24 + j;
    A0 = MFMA_F16(av, *(const f16x8*)(w0 + kt * 512), A0);
    A1 = MFMA_F16(av, *(const f16x8*)(w0 + 16384 + kt * 512), A1);
    A2 = MFMA_F16(av, *(const f16x8*)(w0 + 32768 + kt * 512), A2);
  }
}

__global__ __launch_bounds__(256, 1) void k_scan(Ptrs p) {
  extern __shared__ char smem[];
  f16* L = (f16*)smem;
  const int b = blockIdx.x, tid = threadIdx.x;
  const int w = tid >> 6, l = tid & 63;
  const int lm = l & 15, lq = l >> 4;

  // ---- one-time: stage weights into LDS (resident), preload biases ----
  {
    auto cp = [&](int dstF16, const f16* src, int nF16) {
      uint4* d = (uint4*)smem + (dstF16 >> 3);
      const uint4* s = (const uint4*)src;
      for (int i = tid; i < (nF16 >> 3); i += 256) d[i] = s[i];
    };
    if (b < 64) {
      cp(0,     p.wih0aP + (size_t)b * 16384, 16384);
      cp(16384, p.wih0aP + (size_t)(64 + b) * 16384, 16384);
      cp(32768, p.wih0aP + (size_t)(128 + b) * 16384, 16384);
      cp(49152, p.wih0bP + (size_t)b * 6144, 6144);
      cp(55296, p.wih0bP + (size_t)(64 + b) * 6144, 6144);
      cp(61440, p.wih0bP + (size_t)(128 + b) * 6144, 6144);
    } else if (b < 128) {
      int cb = b - 64;
      cp(0,     p.wih1P + (size_t)cb * 16384, 16384);
      cp(16384, p.wih1P + (size_t)(64 + cb) * 16384, 16384);
      cp(32768, p.wih1P + (size_t)(128 + cb) * 16384, 16384);
      cp(49152, p.embWP + (size_t)cb * 6144, 6144);
      if (cb < 8) {
        cp(55296, p.predWP + (size_t)cb * 16384, 16384);
        float* lnS = (float*)(smem + 143360);
        for (int i2 = tid; i2 < 1024; i2 += 256) {
          lnS[i2] = p.ln_g[i2];
          lnS[1024 + i2] = p.ln_b[i2];
        }
      }
    } else if (b < 192) {
      int i = b - 128;
      cp(0,     p.whh0P + (size_t)i * 16384, 16384);
      cp(16384, p.whh0P + (size_t)(64 + i) * 16384, 16384);
      cp(32768, p.whh0P + (size_t)(128 + i) * 16384, 16384);
    } else {
      int i = b - 192;
      cp(0,     p.whh1P + (size_t)i * 16384, 16384);
      cp(16384, p.whh1P + (size_t)(64 + i) * 16384, 16384);
      cp(32768, p.whh1P + (size_t)(128 + i) * 16384, 16384);
    }
  }
  // per-lane constant biases
  float b0r = 0.f, b1r = 0.f, b2r = 0.f, ebr = 0.f, pbr = 0.f;
  if (b < 64) {
    int col = b * 16 + lm;
    b0r = p.bih0[col]; b1r = p.bih0[1024 + col]; b2r = p.bih0[2048 + col];
  } else if (b < 128) {
    int col = (b - 64) * 16 + lm;
    b0r = p.bih1[col]; b1r = p.bih1[1024 + col]; b2r = p.bih1[2048 + col];
    ebr = p.embB[col];
    if (b < 72) pbr = (col < 126) ? p.predB[col] : 0.f;
  } else if (b < 192) {
    int col = (b - 128) * 16 + lm;
    b0r = p.bhh0[col]; b1r = p.bhh0[1024 + col]; b2r = p.bhh0[2048 + col];
  } else {
    int col = (b - 192) * 16 + lm;
    b0r = p.bhh1[col]; b1r = p.bhh1[1024 + col]; b2r = p.bhh1[2048 + col];
  }
  __syncthreads();

  unsigned* bar = p.bar;

  for (unsigned t = 0; t < TSTEPS; t++) {
    const f16* xc = p.xcat + (size_t)t * 24576;

    if (b < 64) {
      // ================= BB: P1 (gip in regs) then B (h0n) =================
      // static k-tiles 4..11 BEFORE the S4 wait (xcat aud/lxm/style known since prologue)
      f32x4 a0 = {0,0,0,0}, a1 = {0,0,0,0}, a2 = {0,0,0,0};
      const f16* aB = xc + (w * 16 + lm) * 384 + lq * 8;
      const f16* wl = L + 49152 + l * 8;
      #pragma unroll
      for (int kt = 4; kt < 12; kt++) {
        f16x8 av = *(const f16x8*)(aB + kt * 32);
        a0 = MFMA_F16(av, *(const f16x8*)(wl + kt * 512), a0);
        a1 = MFMA_F16(av, *(const f16x8*)(wl + 6144 + kt * 512), a1);
        a2 = MFMA_F16(av, *(const f16x8*)(wl + 12288 + kt * 512), a2);
      }
      if (t) waitc(bar, S4, t);
      f32x4 gip0, gip1, gip2;
      {
        u64 up[8];
        #pragma unroll
        for (int kt = 0; kt < 4; kt++) { up[2*kt] = ldc8(aB + kt * 32); up[2*kt+1] = ldc8(aB + kt * 32 + 4); }
        #pragma unroll
        for (int kt = 0; kt < 4; kt++) {
          f16x8 av = toH(up[2*kt], up[2*kt+1]);
          a0 = MFMA_F16(av, *(const f16x8*)(wl + kt * 512), a0);
          a1 = MFMA_F16(av, *(const f16x8*)(wl + 6144 + kt * 512), a1);
          a2 = MFMA_F16(av, *(const f16x8*)(wl + 12288 + kt * 512), a2);
        }
        #pragma unroll
        for (int r = 0; r < 4; r++) {
          gip0[r] = a0[r] + b0r; gip1[r] = a1[r] + b1r; gip2[r] = a2[r] + b2r;
        }
      }
      waitc2(bar, S1, 8 * (t + 1), S3B, 8 * t);
      {
        const float* rec = p.ghP0 + ((size_t)((b * 16 + lm) * 16 + w * 4 + lq)) * 16;
        u64 r0 = ldc8(rec), r1 = ldc8(rec + 2), r2 = ldc8(rec + 4);
        u64 r3 = ldc8(rec + 6), r4 = ldc8(rec + 8), r5 = ldc8(rec + 10);
        f32x4 A0 = {0,0,0,0}, A1 = {0,0,0,0}, A2 = {0,0,0,0};
        gemm3(p.ineB + (w * 16 + lm) * 1024 + lq * 8, L, l, A0, A1, A2);
        f32x4 g0 = toF(r0, r1), g1 = toF(r2, r3), g2 = toF(r4, r5);
        int col = b * 16 + lm;
        #pragma unroll
        for (int r = 0; r < 4; r++) {
          int row = w * 16 + lq * 4 + r;
          float r_ = sigmf(A0[r] + gip0[r] + g0[r]);
          float z_ = sigmf(A1[r] + gip1[r] + g1[r]);
          float n_ = tanhf(A2[r] + gip2[r] + r_ * g2[r]);
          float* hf = p.h0F + (size_t)row * 1024 + col;
          float hn = (1.f - z_) * n_ + z_ * (*hf);
          *hf = hn;
          st_pair(p.h0B + (size_t)row * 1024 + col, hn, lm, true);
        }
      }
      sigc(bar, S2, b);
    } else if (b < 128) {
      // ================= CB: P1 (ine) then C (h1n); cb<8 also pred =================
      int cb = b - 64;
      int col = cb * 16 + lm;
      // static ine k-tiles before S4 wait
      f32x4 acc = {0,0,0,0};
      const f16* aB = xc + (w * 16 + lm) * 384 + lq * 8;
      const f16* wl = L + 49152 + l * 8;
      #pragma unroll
      for (int kt = 4; kt < 12; kt++)
        acc = MFMA_F16(*(const f16x8*)(aB + kt * 32), *(const f16x8*)(wl + kt * 512), acc);
      if (t) waitc(bar, S4, t);
      {
        u64 up[8];
        #pragma unroll
        for (int kt = 0; kt < 4; kt++) { up[2*kt] = ldc8(aB + kt * 32); up[2*kt+1] = ldc8(aB + kt * 32 + 4); }
        #pragma unroll
        for (int kt = 0; kt < 4; kt++)
          acc = MFMA_F16(toH(up[2*kt], up[2*kt+1]), *(const f16x8*)(wl + kt * 512), acc);
        #pragma unroll
        for (int r = 0; r < 4; r++) {
          int row = w * 16 + lq * 4 + r;
          float v = geluf(acc[r] + ebr);
          st_pair(p.ineB + (size_t)row * 1024 + col, v, lm, true);
        }
      }
      sigc(bar, S1, b);
      waitc2(bar, S2, 8 * (t + 1), S4G, 8 * t);
      {
        const float* rec = p.ghP1 + ((size_t)((cb * 16 + lm) * 16 + w * 4 + lq)) * 16;
        u64 r0 = ldc8(rec), r1 = ldc8(rec + 2), r2 = ldc8(rec + 4);
        u64 r3 = ldc8(rec + 6), r4 = ldc8(rec + 8), r5 = ldc8(rec + 10);
        f32x4 A0 = {0,0,0,0}, A1 = {0,0,0,0}, A2 = {0,0,0,0};
        gemm3(p.h0B + (w * 16 + lm) * 1024 + lq * 8, L, l, A0, A1, A2);
        f32x4 g0 = toF(r0, r1), g1 = toF(r2, r3), g2 = toF(r4, r5);
        float sv[4], sq[4];
        #pragma unroll
        for (int r = 0; r < 4; r++) {
          int row = w * 16 + lq * 4 + r;
          float r_ = sigmf(A0[r] + b0r + g0[r]);
          float z_ = sigmf(A1[r] + b1r + g1[r]);
          float n_ = tanhf(A2[r] + b2r + r_ * g2[r]);
          float* hf = p.h1F + (size_t)row * 1024 + col;
          float hn = (1.f - z_) * n_ + z_ * (*hf);
          *hf = hn;
          st_pair(p.h1B + (size_t)row * 1024 + col, hn, lm, true);
          sv[r] = hn; sq[r] = hn * hn;
        }
        #pragma unroll
        for (int m = 1; m < 16; m <<= 1) {
          #pragma unroll
          for (int r = 0; r < 4; r++) { sv[r] += __shfl_xor(sv[r], m); sq[r] += __shfl_xor(sq[r], m); }
        }
        if (lm == 0) {
          #pragma unroll
          for (int r = 0; r < 4; r++) {
            int row = w * 16 + lq * 4 + r;
            stc8(&p.part[cb * 128 + row * 2], packF2(sv[r], sq[r]));
          }
        }
      }
      sigc(bar, S3, b);
      if (cb < 8) {
        // ---- pred: this block just produced S3, so it detects completion fastest ----
        waitc(bar, S3, 8 * (t + 1));
        float* lnS = (float*)(smem + 143360);
        float* redS = (float*)(smem + 151552);
        float* statsS = (float*)(smem + 155648);
        {  // reduce part: 64 blocks x 128 entries
          int gg = tid >> 5, j4 = tid & 31;
          u64 pu[16];
          #pragma unroll
          for (int c = 0; c < 8; c++) {
            const float* q = p.part + ((gg * 8 + c) * 128 + j4 * 4);
            pu[2*c] = ldc8(q); pu[2*c+1] = ldc8(q + 2);
          }
          f32x4 s = {0,0,0,0};
          #pragma unroll
          for (int c = 0; c < 8; c++) s += toF(pu[2*c], pu[2*c+1]);
          *(f32x4*)(redS + gg * 128 + j4 * 4) = s;
        }
        __syncthreads();
        if (tid < 128) {
          float v = 0.f;
          #pragma unroll
          for (int gg = 0; gg < 8; gg++) v += redS[gg * 128 + tid];
          statsS[tid] = v;
        }
        __syncthreads();
        int myrow = w * 16 + lm;
        float mean = statsS[myrow * 2] * 0.0009765625f;
        float var  = statsS[myrow * 2 + 1] * 0.0009765625f - mean * mean;
        float rstd = rsqrtf(var + 1e-5f);
        f32x4 pacc = {0,0,0,0};
        const f16* hB = p.h1B + (size_t)myrow * 1024 + lq * 8;
        const f16* wp = L + 55296 + l * 8;
        u64 ua[16], ub[16];
        #pragma unroll
        for (int j = 0; j < 8; j++) { ua[2*j] = ldc8(hB + j * 32); ua[2*j+1] = ldc8(hB + j * 32 + 4); }
        #pragma unroll
        for (int j = 0; j < 8; j++) { ub[2*j] = ldc8(hB + 256 + j * 32); ub[2*j+1] = ldc8(hB + 256 + j * 32 + 4); }
        auto compP = [&](u64* cur, int g) {
          #pragma unroll
          for (int j = 0; j < 8; j++) {
            int kt = g * 8 + j, k0 = kt * 32 + lq * 8;
            f16x8 hv = toH(cur[2*j], cur[2*j+1]);
            f16x8 af;
            #pragma unroll
            for (int e = 0; e < 8; e++)
              af[e] = (f16)(((float)hv[e] - mean) * rstd * lnS[k0 + e] + lnS[1024 + k0 + e]);
            pacc = MFMA_F16(af, *(const f16x8*)(wp + kt * 512), pacc);
          }
        };
        compP(ua, 0);
        #pragma unroll
        for (int j = 0; j < 8; j++) { ua[2*j] = ldc8(hB + 512 + j * 32); ua[2*j+1] = ldc8(hB + 512 + j * 32 + 4); }
        compP(ub, 1);
        #pragma unroll
        for (int j = 0; j < 8; j++) { ub[2*j] = ldc8(hB + 768 + j * 32); ub[2*j+1] = ldc8(hB + 768 + j * 32 + 4); }
        compP(ua, 2);
        compP(ub, 3);
        #pragma unroll
        for (int r = 0; r < 4; r++) {
          int row = w * 16 + lq * 4 + r;
          float v = pacc[r] + pbr;
          if (col < 126) stcf(&p.predsT[(size_t)t * 8064 + row * 126 + col], v);
          st_pair(p.xcat + (size_t)(t + 1) * 24576 + row * 384 + col, v, lm,
                  col < 126 && t < 447);
        }
        sigc(bar, S4, b);
      }
    } else if (b < 192) {
      // ================= GH0: gh0(t+1) =================
      int i = b - 128;
      waitc(bar, S2, 8 * (t + 1));
      {
        f32x4 A0 = {0,0,0,0}, A1 = {0,0,0,0}, A2 = {0,0,0,0};
        gemm3(p.h0B + (w * 16 + lm) * 1024 + lq * 8, L, l, A0, A1, A2);
        float* rec = p.ghP0 + ((size_t)((i * 16 + lm) * 16 + w * 4 + lq)) * 16;
        stc8(rec,      packF2(A0[0] + b0r, A0[1] + b0r));
        stc8(rec + 2,  packF2(A0[2] + b0r, A0[3] + b0r));
        stc8(rec + 4,  packF2(A1[0] + b1r, A1[1] + b1r));
        stc8(rec + 6,  packF2(A1[2] + b1r, A1[3] + b1r));
        stc8(rec + 8,  packF2(A2[0] + b2r, A2[1] + b2r));
        stc8(rec + 10, packF2(A2[2] + b2r, A2[3] + b2r));
      }
      sigc(bar, S3B, b);
    } else {
      // ================= GH1: gh1(t+1) =================
      int i = b - 192;
      waitc(bar, S3, 8 * (t + 1));
      {
        f32x4 A0 = {0,0,0,0}, A1 = {0,0,0,0}, A2 = {0,0,0,0};
        gemm3(p.h1B + (w * 16 + lm) * 1024 + lq * 8, L, l, A0, A1, A2);
        float* rec = p.ghP1 + ((size_t)((i * 16 + lm) * 16 + w * 4 + lq)) * 16;
        stc8(rec,      packF2(A0[0] + b0r, A0[1] + b0r));
        stc8(rec + 2,  packF2(A0[2] + b0r, A0[3] + b0r));
        stc8(rec + 4,  packF2(A1[0] + b1r, A1[1] + b1r));
        stc8(rec + 6,  packF2(A1[2] + b1r, A1[3] + b1r));
        stc8(rec + 8,  packF2(A2[0] + b2r, A2[1] + b2r));
        stc8(rec + 10, packF2(A2[2] + b2r, A2[3] + b2r));
      }
      sigc(bar, S4G, b);
    }
  }

  // ======== epilogue: predsT (t,n,m) -> out (n,m,t) ========
  waitc(bar, S4, TSTEPS);
  {
    float* trS = (float*)smem;
    for (int g = b; g < 504; g += 256) {
      int p0 = g * 16;
      for (int t0 = 0; t0 < 448; t0 += 16) {
        int tc = tid >> 4, pp = tid & 15;
        trS[tc * 17 + pp] = p.predsT[(size_t)(t0 + tc) * 8064 + p0 + pp];
        __syncthreads();
        p.out[(size_t)(p0 + (tid >> 4)) * 448 + t0 + (tid & 15)] = trS[(tid & 15) * 17 + (tid >> 4)];
        __syncthreads();
      }
    }
  }
}

// ---------------- host ----------------

extern "C" void kernel_launch(void* const* d_in, const int* in_sizes, int n_in,
                              void* d_out, int out_size, void* d_ws, size_t ws_size,
                              hipStream_t stream) {
  Ptrs p;
  p.aud = (const float*)d_in[0];
  p.mo  = (const float*)d_in[1];
  p.lxm = (const float*)d_in[2];
  p.vid = (const int*)d_in[3];
  p.eps = (const float*)d_in[4];
  p.csi_w0 = (const float*)d_in[5];  p.csi_b0 = (const float*)d_in[6];
  p.csi_w1 = (const float*)d_in[7];  p.csi_b1 = (const float*)d_in[8];
  p.csi_w2 = (const float*)d_in[9];  p.csi_b2 = (const float*)d_in[10];
  p.spk  = (const float*)d_in[11];
  p.mu_w = (const float*)d_in[12];   p.mu_b = (const float*)d_in[13];
  p.lv_w = (const float*)d_in[14];   p.lv_b = (const float*)d_in[15];
  p.embW = (const float*)d_in[16];   p.embB = (const float*)d_in[17];
  p.wih0 = (const float*)d_in[18];   p.whh0 = (const float*)d_in[19];
  p.bih0 = (const float*)d_in[20];   p.bhh0 = (const float*)d_in[21];
  p.wih1 = (const float*)d_in[22];   p.whh1 = (const float*)d_in[23];
  p.bih1 = (const float*)d_in[24];   p.bhh1 = (const float*)d_in[25];
  p.ln_g = (const float*)d_in[26];   p.ln_b = (const float*)d_in[27];
  p.predW = (const float*)d_in[28];  p.predB = (const float*)d_in[29];
  p.out = (float*)d_out;

  char* ws = (char*)d_ws;
  size_t off = 0;
  auto al = [&](size_t bytes) -> void* {
    void* r = (void*)(ws + off);
    off += (bytes + 255) & ~(size_t)255;
    return r;
  };
  p.bar    = (unsigned*)al(8192);
  p.part   = (float*)al(32768);
  p.mu5    = (float*)al(640);
  p.lv5    = (float*)al(640);
  p.h0F    = (float*)al(262144);
  p.h1F    = (float*)al(262144);
  p.h0B    = (f16*)al(131072);
  p.h1B    = (f16*)al(131072);
  p.ineB   = (f16*)al(131072);
  p.ghP0   = (float*)al(1048576);
  p.ghP1   = (float*)al(1048576);
  p.x0     = (float*)al(262144);
  p.x1     = (float*)al(262144);
  p.predsT = (float*)al(14450688);
  p.xcat   = (f16*)al(22020096);
  p.whh0P  = (f16*)al(6291456);
  p.whh1P  = (f16*)al(6291456);
  p.wih0aP = (f16*)al(6291456);
  p.wih0bP = (f16*)al(2359296);
  p.wih1P  = (f16*)al(6291456);
  p.embWP  = (f16*)al(786432);
  p.predWP = (f16*)al(262144);

  k_init<<<8, 256, 0, stream>>>(p);

  k_pack<<<dim3(192, 32), 256, 0, stream>>>(p.whh0, p.whh0P, 1024, 0, 3072, 3072);
  k_pack<<<dim3(192, 32), 256, 0, stream>>>(p.whh1, p.whh1P, 1024, 0, 3072, 3072);
  k_pack<<<dim3(192, 32), 256, 0, stream>>>(p.wih0, p.wih0aP, 1024, 0, 3072, 3072);
  k_pack<<<dim3(192, 12), 256, 0, stream>>>(p.wih0, p.wih0bP, 382, 1024, 3072, 3072);
  k_pack<<<dim3(192, 32), 256, 0, stream>>>(p.wih1, p.wih1P, 1024, 0, 3072, 3072);
  k_pack<<<dim3(64, 12), 256, 0, stream>>>(p.embW, p.embWP, 382, 0, 1024, 1024);
  k_pack<<<dim3(8, 32), 256, 0, stream>>>(p.predW, p.predWP, 1024, 0, 126, 126);

  k_csi1<<<256, 256, 0, stream>>>(p);
  k_csi2<<<256, 256, 0, stream>>>(p);
  k_csi3<<<512, 256, 0, stream>>>(p);
  k_gh<<<1536, 256, 0, stream>>>(p);
  k_style1<<<1, 256, 0, stream>>>(p);
  k_style2<<<3584, 256, 0, stream>>>(p);
  k_aud<<<1792, 256, 0, stream>>>(p);
  k_lxm<<<10752, 256, 0, stream>>>(p);
  k_premo0<<<32, 256, 0, stream>>>(p);
  k_padz<<<224, 256, 0, stream>>>(p);

  k_scan<<<256, 256, LDS_BYTES, stream>>>(p);

  (void)in_sizes; (void)n_in; (void)out_size; (void)ws_size;
}